// Round 13
// baseline (188.552 us; speedup 1.0000x reference)
//
#include <hip/hip_runtime.h>

#define HID   2048
#define KD    2048
#define GQ    4
#define HPGQ  4
#define DH    128
#define SEQ   2048
#define NBATCH 2
#define NTOK  (NBATCH * SEQ)   // 4096
#define NQKV  3072

typedef unsigned short u16;
typedef unsigned int   u32;
using bf16x8 = __attribute__((ext_vector_type(8))) __bf16;
using bf16x2 = __attribute__((ext_vector_type(2))) __bf16;
using f32x4  = __attribute__((ext_vector_type(4))) float;
using u32x4  = __attribute__((ext_vector_type(4))) u32;

#if __has_builtin(__builtin_amdgcn_exp2f)
#define FEXP2(x) __builtin_amdgcn_exp2f(x)
#else
#define FEXP2(x) exp2f(x)
#endif

// 1/sqrt(128) * log2(e): folded into Q projection so scores are in log2 domain
#define QSCALE 0.12751744f

__device__ __forceinline__ u16 f2bf(float f) {
  union { float f; u32 u; } v; v.f = f;
  u32 u = v.u + 0x7fffu + ((v.u >> 16) & 1u);
  return (u16)(u >> 16);
}

__device__ __forceinline__ u32 pk2(float a, float b) {
  bf16x2 t;
  t[0] = (__bf16)a;
  t[1] = (__bf16)b;
  return __builtin_bit_cast(u32, t);
}

__device__ __forceinline__ void gl16(const void* g, void* l) {
  __builtin_amdgcn_global_load_lds((const __attribute__((address_space(1))) u32*)g,
                                   (__attribute__((address_space(3))) u32*)l, 16, 0, 0);
}

// staging-side swizzle (only used OUTSIDE hot loops, for lane-invariant offsets)
__device__ __forceinline__ int swz(int r, int c) {
  return (c & ~7) | ((c ^ r ^ (r >> 3)) & 7);
}

// ---------------- fp32 -> bf16 elementwise convert (x) ----------------
__global__ __launch_bounds__(256) void k_cvt_bf16(const float* __restrict__ in,
                                                  u16* __restrict__ out, int n4) {
  int i = blockIdx.x * 256 + threadIdx.x;
  if (i < n4) {
    const float4 v = ((const float4*)in)[i];
    ushort4 o;
    o.x = f2bf(v.x); o.y = f2bf(v.y); o.z = f2bf(v.z); o.w = f2bf(v.w);
    ((ushort4*)out)[i] = o;
  }
}

// ---------------- all weight transposes fused (blockIdx.z selects matrix) ---------
__global__ __launch_bounds__(256) void k_trans_all(
    const float* __restrict__ Wq, const float* __restrict__ Wk,
    const float* __restrict__ Wv, const float* __restrict__ Wo,
    u16* __restrict__ qkvT, u16* __restrict__ WoT) {
  __shared__ float tile[32][33];
  const int z = blockIdx.z;
  const float* W = (z == 0) ? Wq : (z == 1) ? Wk : (z == 2) ? Wv : Wo;
  u16* WT = (z == 3) ? WoT : qkvT;
  const int N = (z == 1 || z == 2) ? 512 : 2048;
  const int rowoff = (z == 1) ? 2048 : (z == 2) ? 2560 : 0;
  const int n0 = blockIdx.x * 32;
  if (n0 >= N) return;
  const int tx = threadIdx.x, ty = threadIdx.y;
  const int k0 = blockIdx.y * 32;
#pragma unroll
  for (int i = 0; i < 4; ++i)
    tile[ty + 8 * i][tx] = W[(size_t)(k0 + ty + 8 * i) * N + (n0 + tx)];
  __syncthreads();
#pragma unroll
  for (int i = 0; i < 4; ++i)
    WT[(size_t)(rowoff + n0 + ty + 8 * i) * KD + (k0 + tx)] = f2bf(tile[tx][ty + 8 * i]);
}

// ================= 256x192 8-wave pipelined GEMM (QKV) =================
// grid 16x16 = 256 blocks = exactly 1/CU. BK=64, 512 threads = 8 waves (2M x 4N),
// per-wave output 128x48 (8m x 3nt frags). LDS: 2 x (A 32KB + B 24KB) = 112 KiB.
// 4 gray-coded phases/K-tile; staging spread to P2 (B) / P3 (A) + vmcnt(7).

#define QBUF 114688
#define BUFB 57344

#define STG128(OP, ROWB, KTB, LBYTE)                                               \
  { _Pragma("unroll") for (int i = 0; i < 2; ++i)                                  \
      gl16((OP) + (size_t)(ROWB) * KD + (KTB) + stOffE[i],                         \
           (u16*)((char*)S + (LBYTE)) + (i * 512 + t) * 8); }
#define STG64(OP, ROWB, KTB, LBYTE)                                                \
  gl16((OP) + (size_t)(ROWB) * KD + (KTB) + stOffE[0],                             \
       (u16*)((char*)S + (LBYTE)) + t * 8);

#define STAGE_B(D, KTB)                                                            \
  STG128(Bt, n0b,       (KTB), (D) * BUFB + 32768);                                \
  STG64 (Bt, n0b + 128, (KTB), (D) * BUFB + 49152);
#define STAGE_A(D, KTB)                                                            \
  STG128(A,  m0,        (KTB), (D) * BUFB + 0);                                    \
  STG128(A,  m0 + 128,  (KTB), (D) * BUFB + 16384);

#define RDA(D, M, KC) (*(const bf16x8*)((const char*)S + (D) * BUFB + (M) * 2048 + (aQ ^ ((KC) << 6))))
#define RDB(D, NT, KC) (*(const bf16x8*)((const char*)S + (D) * BUFB + (NT) * 2048 + (bQ ^ ((KC) << 6))))

#define MFMA8(MB, NT)                                                              \
  _Pragma("unroll") for (int m = 0; m < 4; ++m)                                    \
    _Pragma("unroll") for (int kc = 0; kc < 2; ++kc)                               \
      acc[(MB) + m][NT] = __builtin_amdgcn_mfma_f32_16x16x32_bf16(                 \
          afr[m][kc], bfr[NT][kc], acc[(MB) + m][NT], 0, 0, 0);

#define ITERQ(D, KTN, PRE)                                                         \
  do {                                                                             \
    /* P0 */                                                                       \
    _Pragma("unroll") for (int m = 0; m < 4; ++m)                                  \
      _Pragma("unroll") for (int kc = 0; kc < 2; ++kc)                             \
        afr[m][kc] = RDA(D, m, kc);                                                \
    _Pragma("unroll") for (int nt = 0; nt < 2; ++nt)                               \
      _Pragma("unroll") for (int kc = 0; kc < 2; ++kc)                             \
        bfr[nt][kc] = RDB(D, nt, kc);                                              \
    asm volatile("s_waitcnt lgkmcnt(8)" ::: "memory");                             \
    __builtin_amdgcn_s_barrier();                                                  \
    __builtin_amdgcn_s_setprio(1);                                                 \
    MFMA8(0, 0) MFMA8(0, 1)                                                        \
    __builtin_amdgcn_s_setprio(0);                                                 \
    __builtin_amdgcn_s_barrier();                                                  \
    /* P1 */                                                                       \
    _Pragma("unroll") for (int kc = 0; kc < 2; ++kc)                               \
      bfr[2][kc] = RDB(D, 2, kc);                                                  \
    __builtin_amdgcn_s_barrier();                                                  \
    __builtin_amdgcn_s_setprio(1);                                                 \
    MFMA8(0, 2)                                                                    \
    __builtin_amdgcn_s_setprio(0);                                                 \
    __builtin_amdgcn_s_barrier();                                                  \
    /* P2 */                                                                       \
    _Pragma("unroll") for (int m = 0; m < 4; ++m)                                  \
      _Pragma("unroll") for (int kc = 0; kc < 2; ++kc)                             \
        afr[m][kc] = RDA(D, 4 + m, kc);                                            \
    if (PRE) { STAGE_B(D, KTN); }                                                  \
    __builtin_amdgcn_s_barrier();                                                  \
    __builtin_amdgcn_s_setprio(1);                                                 \
    MFMA8(4, 2)                                                                    \
    __builtin_amdgcn_s_setprio(0);                                                 \
    __builtin_amdgcn_s_barrier();                                                  \
    /* P3 */                                                                       \
    if (PRE) {                                                                     \
      STAGE_A(D, KTN);                                                             \
      asm volatile("s_waitcnt vmcnt(7)" ::: "memory");                             \
    } else {                                                                       \
      asm volatile("s_waitcnt vmcnt(0)" ::: "memory");                             \
    }                                                                              \
    __builtin_amdgcn_s_barrier();                                                  \
    __builtin_amdgcn_s_setprio(1);                                                 \
    MFMA8(4, 0) MFMA8(4, 1)                                                        \
    __builtin_amdgcn_s_setprio(0);                                                 \
    __builtin_amdgcn_s_barrier();                                                  \
  } while (0)

__global__ __launch_bounds__(512, 1) void k_gemm_qkv(
    const u16* __restrict__ A, const u16* __restrict__ Bt,
    u16* __restrict__ qkv, u16* __restrict__ vT,
    const float* __restrict__ bq, const float* __restrict__ bk,
    const float* __restrict__ bv) {
  __shared__ u16 S[QBUF / 2];                 // 112 KiB
  const int t = threadIdx.x, l = t & 63, w = t >> 6;
  const int lr = l & 15, lk = l >> 4;
  const int wm = w >> 2, wn = w & 3;
  const int m0 = blockIdx.y * 256, n0b = blockIdx.x * 192;

  int stOffE[2];
#pragma unroll
  for (int i = 0; i < 2; ++i) {
    const int e = i * 512 + t;
    const int r = e >> 3;
    stOffE[i] = r * KD + ((e & 7) ^ (r & 7)) * 8;
  }
  const int qb = lr * 128 + (((lr >> 2) & 1) << 6) + ((lk ^ (lr & 3)) << 4);
  const int aQ = wm * 16384 + qb;
  const int bQ = 32768 + wn * 6144 + qb;

  f32x4 acc[8][3] = {};
  bf16x8 afr[4][2], bfr[3][2];

  STAGE_A(0, 0);  STAGE_B(0, 0);
  STAGE_A(1, 64); STAGE_B(1, 64);
  asm volatile("s_waitcnt vmcnt(7)" ::: "memory");
  __builtin_amdgcn_s_barrier();

  for (int j = 0; j < 30; j += 2) {
    ITERQ(0, (j + 2) * 64, true);
    ITERQ(1, (j + 3) * 64, true);
  }
  ITERQ(0, 0, false);
  ITERQ(1, 0, false);

  const int gmB = m0 + wm * 128, gnB = n0b + wn * 48;
#pragma unroll
  for (int m = 0; m < 8; ++m) {
    const int row0 = gmB + m * 16 + lk * 4;
#pragma unroll
    for (int nt = 0; nt < 3; ++nt) {
      const int col = gnB + nt * 16 + lr;
      float bias, qs = 1.0f;
      if (col < HID) { bias = bq[col]; qs = QSCALE; }
      else if (col < HID + 512) bias = bk[col - HID];
      else bias = bv[col - HID - 512];
      if (col < HID + 512) {
#pragma unroll
        for (int r = 0; r < 4; ++r)
          qkv[(size_t)(row0 + r) * NQKV + col] = f2bf((acc[m][nt][r] + bias) * qs);
      } else {
        const int gg = (col - 2560) >> 7, d = (col - 2560) & 127;
        const int b = row0 >> 11, s0 = row0 & 2047;
        ushort4 pk;
        pk.x = f2bf(acc[m][nt][0] + bias);
        pk.y = f2bf(acc[m][nt][1] + bias);
        pk.z = f2bf(acc[m][nt][2] + bias);
        pk.w = f2bf(acc[m][nt][3] + bias);
        *(ushort4*)(vT + ((size_t)(b * GQ + gg) * DH + d) * SEQ + s0) = pk;
      }
    }
  }
}

// ================= O-projection GEMM (128x128, unchanged) =================
#define GEMM_STEP(CUR, NXT, K0N, PRE)                                              \
  do {                                                                             \
    if (PRE) {                                                                     \
      const u16* aB = A  + (size_t)m0 * KD + (K0N);                                \
      const u16* bB = Bt + (size_t)n0 * KD + (K0N);                                \
      _Pragma("unroll")                                                            \
      for (int i = 0; i < 2; ++i) {                                                \
        gl16(aB + stOff[i], So + (NXT)*4096 + (i * 256 + t) * 8);                  \
        gl16(bB + stOff[i], So + 8192 + (NXT)*4096 + (i * 256 + t) * 8);           \
      }                                                                            \
      asm volatile("s_waitcnt vmcnt(4)" ::: "memory");                             \
    } else {                                                                       \
      asm volatile("s_waitcnt vmcnt(0)" ::: "memory");                             \
    }                                                                              \
    __builtin_amdgcn_s_barrier();                                                  \
    bf16x8 af[4], bfr[4];                                                          \
    _Pragma("unroll")                                                              \
    for (int m = 0; m < 4; ++m)                                                    \
      af[m] = *(const bf16x8*)((const char*)So + (CUR)*8192 + m * 1024 + aAddr);   \
    _Pragma("unroll")                                                              \
    for (int n = 0; n < 4; ++n)                                                    \
      bfr[n] = *(const bf16x8*)((const char*)So + 16384 + (CUR)*8192 + n * 1024 + bAddr); \
    __builtin_amdgcn_s_setprio(1);                                                 \
    _Pragma("unroll")                                                              \
    for (int m = 0; m < 4; ++m)                                                    \
      _Pragma("unroll")                                                            \
      for (int n = 0; n < 4; ++n)                                                  \
        acc[m][n] = __builtin_amdgcn_mfma_f32_16x16x32_bf16(af[m], bfr[n], acc[m][n], 0, 0, 0); \
    __builtin_amdgcn_s_setprio(0);                                                 \
    __builtin_amdgcn_s_barrier();                                                  \
  } while (0)

__global__ __launch_bounds__(256) void k_gemm_o(
    const u16* __restrict__ A, const u16* __restrict__ Bt,
    const float* __restrict__ bo, float* __restrict__ C) {
  __shared__ u16 So[16384];
  const int t = threadIdx.x, l = t & 63, w = t >> 6;
  const int lr = l & 15, lk = l >> 4;
  const int wr = w >> 1, wc = w & 1;
  const int m0 = blockIdx.y * 128, n0 = blockIdx.x * 128;
  int stOff[2];
#pragma unroll
  for (int i = 0; i < 2; ++i) {
    const int e = i * 256 + t;
    const int r = e >> 2;
    const int cs = (e & 3) ^ ((r >> 1) & 3);
    stOff[i] = r * KD + cs * 8;
  }
  const int axor = (lk ^ ((lr >> 1) & 3)) << 4;
  const int aAddr = (wr * 64 + lr) * 64 + axor;
  const int bAddr = (wc * 64 + lr) * 64 + axor;
  f32x4 acc[4][4] = {};
  {
    const u16* aB = A  + (size_t)m0 * KD;
    const u16* bB = Bt + (size_t)n0 * KD;
#pragma unroll
    for (int i = 0; i < 2; ++i) {
      gl16(aB + stOff[i], So + (i * 256 + t) * 8);
      gl16(bB + stOff[i], So + 8192 + (i * 256 + t) * 8);
    }
  }
  for (int kt = 0; kt < KD / 32 - 2; kt += 2) {
    GEMM_STEP(0, 1, (kt + 1) * 32, true);
    GEMM_STEP(1, 0, (kt + 2) * 32, true);
  }
  GEMM_STEP(0, 1, (KD / 32 - 1) * 32, true);
  GEMM_STEP(1, 0, 0, false);

  const int gm = m0 + wr * 64, gn = n0 + wc * 64;
#pragma unroll
  for (int m = 0; m < 4; ++m) {
    const int row0 = gm + m * 16 + lk * 4;
#pragma unroll
    for (int n = 0; n < 4; ++n) {
      const int col = gn + n * 16 + lr;
      const float bias = bo[col];
#pragma unroll
      for (int r = 0; r < 4; ++r)
        C[(size_t)(row0 + r) * HID + col] = acc[m][n][r] + bias;
    }
  }
}

// ================= Flash attention =================
// QBLK=128 (4 waves x 32 q), KVBLK=64, dbuf K/V (64 KiB LDS), 512 blocks (2/CU).
// 32 iterations (half the barrier crossings of KVBLK=32). XCD pinning bg=f&7;
// rotated KV order; swapped QK^T; P in registers; no-max softmax (log2 domain).
// K read byte = kQ0 ^ (mk<<12 ^ (kk>>1)<<7 ^ (kk&1)<<6 ^ mk<<5)
// V read byte = vQ0 ^ (nd<<11 ^ s<<6 ^ (nd&3)<<5)

#define ATTN_ITER(KS, VS, KN, VN, TTV, PRE)                                        \
  do {                                                                             \
    if (PRE) {                                                                     \
      const int t0n = ((start + (TTV) + 1) & (NT - 1)) * 64;                       \
      const u16* kbT = kbase + (size_t)t0n * NQKV;                                 \
      const u16* vbT = vbase + t0n;                                                \
      _Pragma("unroll")                                                            \
      for (int i = 0; i < 4; ++i) {                                                \
        gl16(kbT + kOffE[i], (KN) + (i * 256 + t) * 8);                            \
        gl16(vbT + vOffE[i], (VN) + (i * 256 + t) * 8);                            \
      }                                                                            \
      asm volatile("s_waitcnt vmcnt(8)" ::: "memory");                             \
    } else {                                                                       \
      asm volatile("s_waitcnt vmcnt(0)" ::: "memory");                             \
    }                                                                              \
    __builtin_amdgcn_s_barrier();                                                  \
    f32x4 sc[2][4] = {};                                                           \
    __builtin_amdgcn_s_setprio(1);                                                 \
    _Pragma("unroll")                                                              \
    for (int kk = 0; kk < 4; ++kk) {                                               \
      bf16x8 kf[4];                                                                \
      _Pragma("unroll")                                                            \
      for (int mk = 0; mk < 4; ++mk) {                                             \
        const int LIT = (mk << 12) ^ ((kk >> 1) << 7) ^ ((kk & 1) << 6) ^ (mk << 5); \
        kf[mk] = *(const bf16x8*)((const char*)(KS) + (kQ0 ^ LIT));                \
      }                                                                            \
      _Pragma("unroll")                                                            \
      for (int nq = 0; nq < 2; ++nq)                                               \
        _Pragma("unroll")                                                          \
        for (int mk = 0; mk < 4; ++mk)                                             \
          sc[nq][mk] = __builtin_amdgcn_mfma_f32_16x16x32_bf16(kf[mk], qf[nq][kk], sc[nq][mk], 0, 0, 0); \
    }                                                                              \
    __builtin_amdgcn_s_setprio(0);                                                 \
    _Pragma("unroll")                                                              \
    for (int s = 0; s < 2; ++s) {                                                  \
      bf16x8 pa[2];                                                                \
      _Pragma("unroll")                                                            \
      for (int nq = 0; nq < 2; ++nq) {                                             \
        u32 w0 = pk2(FEXP2(sc[nq][2 * s][0]),     FEXP2(sc[nq][2 * s][1]));        \
        u32 w1 = pk2(FEXP2(sc[nq][2 * s][2]),     FEXP2(sc[nq][2 * s][3]));        \
        u32 w2 = pk2(FEXP2(sc[nq][2 * s + 1][0]), FEXP2(sc[nq][2 * s + 1][1]));    \
        u32 w3 = pk2(FEXP2(sc[nq][2 * s + 1][2]), FEXP2(sc[nq][2 * s + 1][3]));    \
        asm("v_permlane32_swap_b32 %0, %1" : "+v"(w0), "+v"(w2));                  \
        asm("v_permlane32_swap_b32 %0, %1" : "+v"(w1), "+v"(w3));                  \
        asm("v_permlane16_swap_b32 %0, %1" : "+v"(w0), "+v"(w2));                  \
        asm("v_permlane16_swap_b32 %0, %1" : "+v"(w1), "+v"(w3));                  \
        u32x4 u = {w0, w1, w2, w3};                                                \
        pa[nq] = __builtin_bit_cast(bf16x8, u);                                    \
      }                                                                            \
      __builtin_amdgcn_s_setprio(1);                                               \
      _Pragma("unroll")                                                            \
      for (int nq = 0; nq < 2; ++nq)                                               \
        acc_s[nq] = __builtin_amdgcn_mfma_f32_16x16x32_bf16(pa[nq], vones, acc_s[nq], 0, 0, 0); \
      _Pragma("unroll")                                                            \
      for (int nd = 0; nd < 8; ++nd) {                                             \
        const int VL = (nd << 11) ^ (s << 6) ^ ((nd & 3) << 5);                    \
        const bf16x8 vf = *(const bf16x8*)((const char*)(VS) + (vQ0 ^ VL));        \
        _Pragma("unroll")                                                          \
        for (int nq = 0; nq < 2; ++nq)                                             \
          acc_o[nq][nd] = __builtin_amdgcn_mfma_f32_16x16x32_bf16(pa[nq], vf, acc_o[nq][nd], 0, 0, 0); \
      }                                                                            \
      __builtin_amdgcn_s_setprio(0);                                               \
    }                                                                              \
    __builtin_amdgcn_s_barrier();                                                  \
  } while (0)

__global__ __launch_bounds__(256, 2) void k_attn(
    const u16* __restrict__ qkv, const u16* __restrict__ vT, u16* __restrict__ o_ws) {
  __shared__ u16 smem[32768];                 // 64 KiB -> 2 blocks/CU
  u16* const kb0 = smem;                      // 8192 elems (64 t x 128 d)
  u16* const kb1 = smem + 8192;
  u16* const vb0 = smem + 16384;              // 8192 elems (128 d x 64 t)
  u16* const vb1 = smem + 24576;

  const int t = threadIdx.x, l = t & 63, w = t >> 6;
  const int lr = l & 15, lk = l >> 4;
  const int f = blockIdx.x;
  const int bg = f & 7;                        // XCD-pinned (b,g)
  const int h = (f >> 3) & 3;
  const int qt = f >> 5;                       // 0..15
  const int b = bg >> 2, g = bg & 3;
  const int q0 = qt * 128;
  const int qcol = (g * HPGQ + h) * DH;
  const u16* qbase = qkv + (size_t)(b * SEQ) * NQKV;
  const u16* kbase = qbase + HID + g * DH;
  const u16* vbase = vT + (size_t)(b * GQ + g) * DH * SEQ;

  const int NT = SEQ / 64;                     // 32 KV tiles
  const int start = (qt * 5 + h * 9) & (NT - 1);

  // loop-invariant per-lane addressing
  const int P0 = lk ^ (lr & 7) ^ (lr >> 3);
  const int kQ0 = lr * 256 + (P0 << 4);
  const int vQ0 = lr * 128 + (P0 << 4);
  int kOffE[4], vOffE[4];
#pragma unroll
  for (int i = 0; i < 4; ++i) {
    const int e = i * 256 + t;
    const int r = e >> 4, c = e & 15;
    kOffE[i] = r * NQKV + swz(r, c) * 8;
    const int rv = e >> 3, cv = e & 7;
    vOffE[i] = rv * SEQ + swz(rv, cv) * 8;
  }

  // Q fragments: direct global->register (32 q-rows per wave)
  bf16x8 qf[2][4];
#pragma unroll
  for (int nq = 0; nq < 2; ++nq)
#pragma unroll
    for (int kk = 0; kk < 4; ++kk)
      qf[nq][kk] = *(const bf16x8*)(qbase + (size_t)(q0 + w * 32 + nq * 16 + lr) * NQKV +
                                    qcol + kk * 32 + lk * 8);

  // stage first tile
  {
    const int t00 = start * 64;
    const u16* kbT = kbase + (size_t)t00 * NQKV;
    const u16* vbT = vbase + t00;
#pragma unroll
    for (int i = 0; i < 4; ++i) {
      gl16(kbT + kOffE[i], kb0 + (i * 256 + t) * 8);
      gl16(vbT + vOffE[i], vb0 + (i * 256 + t) * 8);
    }
  }

  f32x4 acc_o[2][8] = {};
  f32x4 acc_s[2] = {};

  bf16x8 vones;               // B-fragment: d-col 0 = ones -> row sums
#pragma unroll
  for (int j = 0; j < 8; ++j) vones[j] = (lr == 0) ? (__bf16)1.0f : (__bf16)0.0f;

  for (int tp = 0; tp < NT - 2; tp += 2) {
    ATTN_ITER(kb0, vb0, kb1, vb1, tp, true);
    ATTN_ITER(kb1, vb1, kb0, vb0, tp + 1, true);
  }
  ATTN_ITER(kb0, vb0, kb1, vb1, NT - 2, true);
  ATTN_ITER(kb1, vb1, kb0, vb0, NT - 1, false);

  // epilogue: normalize by the MFMA-computed row sums
#pragma unroll
  for (int nq = 0; nq < 2; ++nq)
#pragma unroll
    for (int r = 0; r < 4; ++r) {
      const float s = __shfl(acc_s[nq][r], l & 48);
      const float inv = 1.0f / s;
      const int q = q0 + w * 32 + nq * 16 + lk * 4 + r;
#pragma unroll
      for (int nd = 0; nd < 8; ++nd) {
        const int d = nd * 16 + lr;
        o_ws[(size_t)(b * SEQ + q) * HID + qcol + d] = f2bf(acc_o[nq][nd][r] * inv);
      }
    }
}

extern "C" void kernel_launch(void* const* d_in, const int* in_sizes, int n_in,
                              void* d_out, int out_size, void* d_ws, size_t ws_size,
                              hipStream_t stream) {
  const float* x  = (const float*)d_in[0];
  const float* Wq = (const float*)d_in[1];
  const float* bq = (const float*)d_in[2];
  const float* Wk = (const float*)d_in[3];
  const float* bk = (const float*)d_in[4];
  const float* Wv = (const float*)d_in[5];
  const float* bv = (const float*)d_in[6];
  const float* Wo = (const float*)d_in[7];
  const float* bo = (const float*)d_in[8];
  float* out = (float*)d_out;

  char* ws = (char*)d_ws;
  u16* x_bf  = (u16*)ws;  ws += (size_t)NTOK * KD * 2;        // 16 MiB (reused as o_ws later)
  u16* qkvT  = (u16*)ws;  ws += (size_t)NQKV * KD * 2;        // 12 MiB
  u16* WoT   = (u16*)ws;  ws += (size_t)HID * KD * 2;         //  8 MiB
  u16* qkv   = (u16*)ws;  ws += (size_t)NTOK * NQKV * 2;      // 24 MiB
  u16* vTb   = (u16*)ws;  ws += (size_t)NBATCH * GQ * DH * SEQ * 2;  // 4 MiB
  u16* o_ws  = x_bf;  // x_bf dead after QKV GEMM; attention output reuses it

  k_cvt_bf16<<<(NTOK * KD / 4 + 255) / 256, 256, 0, stream>>>(x, x_bf, NTOK * KD / 4);
  k_trans_all<<<dim3(64, 64, 4), dim3(32, 8), 0, stream>>>(Wq, Wk, Wv, Wo, qkvT, WoT);

  k_gemm_qkv<<<dim3(NQKV / 192, NTOK / 256), 512, 0, stream>>>(x_bf, qkvT, qkv, vTb, bq, bk, bv);
  k_attn<<<SEQ / 128 * NBATCH * GQ * HPGQ, 256, 0, stream>>>(qkv, vTb, o_ws);
  k_gemm_o<<<dim3(HID / 128, NTOK / 128), 256, 0, stream>>>(o_ws, WoT, bo, out);
}

// Round 14
// 183.447 us; speedup vs baseline: 1.0278x; 1.0278x over previous
//
#include <hip/hip_runtime.h>

#define HID   2048
#define KD    2048
#define GQ    4
#define HPGQ  4
#define DH    128
#define SEQ   2048
#define NBATCH 2
#define NTOK  (NBATCH * SEQ)   // 4096
#define NQKV  3072

typedef unsigned short u16;
typedef unsigned int   u32;
using bf16x8 = __attribute__((ext_vector_type(8))) __bf16;
using bf16x2 = __attribute__((ext_vector_type(2))) __bf16;
using f32x4  = __attribute__((ext_vector_type(4))) float;
using u32x4  = __attribute__((ext_vector_type(4))) u32;

#if __has_builtin(__builtin_amdgcn_exp2f)
#define FEXP2(x) __builtin_amdgcn_exp2f(x)
#else
#define FEXP2(x) exp2f(x)
#endif

// 1/sqrt(128) * log2(e): folded into Q projection so scores are in log2 domain
#define QSCALE 0.12751744f

__device__ __forceinline__ u16 f2bf(float f) {
  union { float f; u32 u; } v; v.f = f;
  u32 u = v.u + 0x7fffu + ((v.u >> 16) & 1u);
  return (u16)(u >> 16);
}

__device__ __forceinline__ u32 pk2(float a, float b) {
  bf16x2 t;
  t[0] = (__bf16)a;
  t[1] = (__bf16)b;
  return __builtin_bit_cast(u32, t);
}

__device__ __forceinline__ void gl16(const void* g, void* l) {
  __builtin_amdgcn_global_load_lds((const __attribute__((address_space(1))) u32*)g,
                                   (__attribute__((address_space(3))) u32*)l, 16, 0, 0);
}

// staging-side swizzle (only used OUTSIDE hot loops, for lane-invariant offsets)
__device__ __forceinline__ int swz(int r, int c) {
  return (c & ~7) | ((c ^ r ^ (r >> 3)) & 7);
}

// ---------------- fp32 -> bf16 elementwise convert (x) ----------------
__global__ __launch_bounds__(256) void k_cvt_bf16(const float* __restrict__ in,
                                                  u16* __restrict__ out, int n4) {
  int i = blockIdx.x * 256 + threadIdx.x;
  if (i < n4) {
    const float4 v = ((const float4*)in)[i];
    ushort4 o;
    o.x = f2bf(v.x); o.y = f2bf(v.y); o.z = f2bf(v.z); o.w = f2bf(v.w);
    ((ushort4*)out)[i] = o;
  }
}

// ---------------- all weight transposes fused (blockIdx.z selects matrix) ---------
__global__ __launch_bounds__(256) void k_trans_all(
    const float* __restrict__ Wq, const float* __restrict__ Wk,
    const float* __restrict__ Wv, const float* __restrict__ Wo,
    u16* __restrict__ qkvT, u16* __restrict__ WoT) {
  __shared__ float tile[32][33];
  const int z = blockIdx.z;
  const float* W = (z == 0) ? Wq : (z == 1) ? Wk : (z == 2) ? Wv : Wo;
  u16* WT = (z == 3) ? WoT : qkvT;
  const int N = (z == 1 || z == 2) ? 512 : 2048;
  const int rowoff = (z == 1) ? 2048 : (z == 2) ? 2560 : 0;
  const int n0 = blockIdx.x * 32;
  if (n0 >= N) return;
  const int tx = threadIdx.x, ty = threadIdx.y;
  const int k0 = blockIdx.y * 32;
#pragma unroll
  for (int i = 0; i < 4; ++i)
    tile[ty + 8 * i][tx] = W[(size_t)(k0 + ty + 8 * i) * N + (n0 + tx)];
  __syncthreads();
#pragma unroll
  for (int i = 0; i < 4; ++i)
    WT[(size_t)(rowoff + n0 + ty + 8 * i) * KD + (k0 + tx)] = f2bf(tile[tx][ty + 8 * i]);
}

// ================= 256x192 8-wave pipelined GEMM (QKV) — unchanged r12 =========
#define QBUF 114688
#define BUFB 57344

#define STG128(OP, ROWB, KTB, LBYTE)                                               \
  { _Pragma("unroll") for (int i = 0; i < 2; ++i)                                  \
      gl16((OP) + (size_t)(ROWB) * KD + (KTB) + stOffE[i],                         \
           (u16*)((char*)S + (LBYTE)) + (i * 512 + t) * 8); }
#define STG64(OP, ROWB, KTB, LBYTE)                                                \
  gl16((OP) + (size_t)(ROWB) * KD + (KTB) + stOffE[0],                             \
       (u16*)((char*)S + (LBYTE)) + t * 8);

#define STAGE_B(D, KTB)                                                            \
  STG128(Bt, n0b,       (KTB), (D) * BUFB + 32768);                                \
  STG64 (Bt, n0b + 128, (KTB), (D) * BUFB + 49152);
#define STAGE_A(D, KTB)                                                            \
  STG128(A,  m0,        (KTB), (D) * BUFB + 0);                                    \
  STG128(A,  m0 + 128,  (KTB), (D) * BUFB + 16384);

#define RDA(D, M, KC) (*(const bf16x8*)((const char*)S + (D) * BUFB + (M) * 2048 + (aQ ^ ((KC) << 6))))
#define RDB(D, NT, KC) (*(const bf16x8*)((const char*)S + (D) * BUFB + (NT) * 2048 + (bQ ^ ((KC) << 6))))

#define MFMA8(MB, NT)                                                              \
  _Pragma("unroll") for (int m = 0; m < 4; ++m)                                    \
    _Pragma("unroll") for (int kc = 0; kc < 2; ++kc)                               \
      acc[(MB) + m][NT] = __builtin_amdgcn_mfma_f32_16x16x32_bf16(                 \
          afr[m][kc], bfr[NT][kc], acc[(MB) + m][NT], 0, 0, 0);

#define ITERQ(D, KTN, PRE)                                                         \
  do {                                                                             \
    /* P0 */                                                                       \
    _Pragma("unroll") for (int m = 0; m < 4; ++m)                                  \
      _Pragma("unroll") for (int kc = 0; kc < 2; ++kc)                             \
        afr[m][kc] = RDA(D, m, kc);                                                \
    _Pragma("unroll") for (int nt = 0; nt < 2; ++nt)                               \
      _Pragma("unroll") for (int kc = 0; kc < 2; ++kc)                             \
        bfr[nt][kc] = RDB(D, nt, kc);                                              \
    asm volatile("s_waitcnt lgkmcnt(8)" ::: "memory");                             \
    __builtin_amdgcn_s_barrier();                                                  \
    __builtin_amdgcn_s_setprio(1);                                                 \
    MFMA8(0, 0) MFMA8(0, 1)                                                        \
    __builtin_amdgcn_s_setprio(0);                                                 \
    __builtin_amdgcn_s_barrier();                                                  \
    /* P1 */                                                                       \
    _Pragma("unroll") for (int kc = 0; kc < 2; ++kc)                               \
      bfr[2][kc] = RDB(D, 2, kc);                                                  \
    __builtin_amdgcn_s_barrier();                                                  \
    __builtin_amdgcn_s_setprio(1);                                                 \
    MFMA8(0, 2)                                                                    \
    __builtin_amdgcn_s_setprio(0);                                                 \
    __builtin_amdgcn_s_barrier();                                                  \
    /* P2 */                                                                       \
    _Pragma("unroll") for (int m = 0; m < 4; ++m)                                  \
      _Pragma("unroll") for (int kc = 0; kc < 2; ++kc)                             \
        afr[m][kc] = RDA(D, 4 + m, kc);                                            \
    if (PRE) { STAGE_B(D, KTN); }                                                  \
    __builtin_amdgcn_s_barrier();                                                  \
    __builtin_amdgcn_s_setprio(1);                                                 \
    MFMA8(4, 2)                                                                    \
    __builtin_amdgcn_s_setprio(0);                                                 \
    __builtin_amdgcn_s_barrier();                                                  \
    /* P3 */                                                                       \
    if (PRE) {                                                                     \
      STAGE_A(D, KTN);                                                             \
      asm volatile("s_waitcnt vmcnt(7)" ::: "memory");                             \
    } else {                                                                       \
      asm volatile("s_waitcnt vmcnt(0)" ::: "memory");                             \
    }                                                                              \
    __builtin_amdgcn_s_barrier();                                                  \
    __builtin_amdgcn_s_setprio(1);                                                 \
    MFMA8(4, 0) MFMA8(4, 1)                                                        \
    __builtin_amdgcn_s_setprio(0);                                                 \
    __builtin_amdgcn_s_barrier();                                                  \
  } while (0)

__global__ __launch_bounds__(512, 1) void k_gemm_qkv(
    const u16* __restrict__ A, const u16* __restrict__ Bt,
    u16* __restrict__ qkv, u16* __restrict__ vT,
    const float* __restrict__ bq, const float* __restrict__ bk,
    const float* __restrict__ bv) {
  __shared__ u16 S[QBUF / 2];                 // 112 KiB
  const int t = threadIdx.x, l = t & 63, w = t >> 6;
  const int lr = l & 15, lk = l >> 4;
  const int wm = w >> 2, wn = w & 3;
  const int m0 = blockIdx.y * 256, n0b = blockIdx.x * 192;

  int stOffE[2];
#pragma unroll
  for (int i = 0; i < 2; ++i) {
    const int e = i * 512 + t;
    const int r = e >> 3;
    stOffE[i] = r * KD + ((e & 7) ^ (r & 7)) * 8;
  }
  const int qb = lr * 128 + (((lr >> 2) & 1) << 6) + ((lk ^ (lr & 3)) << 4);
  const int aQ = wm * 16384 + qb;
  const int bQ = 32768 + wn * 6144 + qb;

  f32x4 acc[8][3] = {};
  bf16x8 afr[4][2], bfr[3][2];

  STAGE_A(0, 0);  STAGE_B(0, 0);
  STAGE_A(1, 64); STAGE_B(1, 64);
  asm volatile("s_waitcnt vmcnt(7)" ::: "memory");
  __builtin_amdgcn_s_barrier();

  for (int j = 0; j < 30; j += 2) {
    ITERQ(0, (j + 2) * 64, true);
    ITERQ(1, (j + 3) * 64, true);
  }
  ITERQ(0, 0, false);
  ITERQ(1, 0, false);

  const int gmB = m0 + wm * 128, gnB = n0b + wn * 48;
#pragma unroll
  for (int m = 0; m < 8; ++m) {
    const int row0 = gmB + m * 16 + lk * 4;
#pragma unroll
    for (int nt = 0; nt < 3; ++nt) {
      const int col = gnB + nt * 16 + lr;
      float bias, qs = 1.0f;
      if (col < HID) { bias = bq[col]; qs = QSCALE; }
      else if (col < HID + 512) bias = bk[col - HID];
      else bias = bv[col - HID - 512];
      if (col < HID + 512) {
#pragma unroll
        for (int r = 0; r < 4; ++r)
          qkv[(size_t)(row0 + r) * NQKV + col] = f2bf((acc[m][nt][r] + bias) * qs);
      } else {
        const int gg = (col - 2560) >> 7, d = (col - 2560) & 127;
        const int b = row0 >> 11, s0 = row0 & 2047;
        ushort4 pk;
        pk.x = f2bf(acc[m][nt][0] + bias);
        pk.y = f2bf(acc[m][nt][1] + bias);
        pk.z = f2bf(acc[m][nt][2] + bias);
        pk.w = f2bf(acc[m][nt][3] + bias);
        *(ushort4*)(vT + ((size_t)(b * GQ + gg) * DH + d) * SEQ + s0) = pk;
      }
    }
  }
}

// ================= 256x128 8-wave pipelined GEMM (O projection) =================
// grid 16x16 = 256 blocks = 1/CU. Per-wave output 128x32 (8m x 2nt, acc 64 VGPR).
// LDS: 2 x (A 32KB + B 16KB) = 96 KiB. Same gray-coded 4-phase schedule as qkv:
// B dead after P1 -> stage B(t+2) at P2; A dead after P2 -> stage A(t+2) at P3;
// vmcnt(6) at P3 drains tile t+1 (6 loads/tile).

#define OBUFB 49152

#define OSTAGE_B(D, KTB)                                                           \
  STG128(Bt, n0b, (KTB), (D) * OBUFB + 32768);
#define OSTAGE_A(D, KTB)                                                           \
  STG128(A,  m0,       (KTB), (D) * OBUFB + 0);                                    \
  STG128(A,  m0 + 128, (KTB), (D) * OBUFB + 16384);

#define ORDA(D, M, KC) (*(const bf16x8*)((const char*)S + (D) * OBUFB + (M) * 2048 + (aQ ^ ((KC) << 6))))
#define ORDB(D, NT, KC) (*(const bf16x8*)((const char*)S + (D) * OBUFB + (NT) * 2048 + (bQ ^ ((KC) << 6))))

#define OMFMA8(MB, NT)                                                             \
  _Pragma("unroll") for (int m = 0; m < 4; ++m)                                    \
    _Pragma("unroll") for (int kc = 0; kc < 2; ++kc)                               \
      acc[(MB) + m][NT] = __builtin_amdgcn_mfma_f32_16x16x32_bf16(                 \
          afr[m][kc], bfr[NT][kc], acc[(MB) + m][NT], 0, 0, 0);

#define ITERO(D, KTN, PRE)                                                         \
  do {                                                                             \
    /* P0 */                                                                       \
    _Pragma("unroll") for (int m = 0; m < 4; ++m)                                  \
      _Pragma("unroll") for (int kc = 0; kc < 2; ++kc)                             \
        afr[m][kc] = ORDA(D, m, kc);                                               \
    _Pragma("unroll") for (int kc = 0; kc < 2; ++kc)                               \
      bfr[0][kc] = ORDB(D, 0, kc);                                                 \
    asm volatile("s_waitcnt lgkmcnt(8)" ::: "memory");                             \
    __builtin_amdgcn_s_barrier();                                                  \
    __builtin_amdgcn_s_setprio(1);                                                 \
    OMFMA8(0, 0)                                                                   \
    __builtin_amdgcn_s_setprio(0);                                                 \
    __builtin_amdgcn_s_barrier();                                                  \
    /* P1 */                                                                       \
    _Pragma("unroll") for (int kc = 0; kc < 2; ++kc)                               \
      bfr[1][kc] = ORDB(D, 1, kc);                                                 \
    __builtin_amdgcn_s_barrier();                                                  \
    __builtin_amdgcn_s_setprio(1);                                                 \
    OMFMA8(0, 1)                                                                   \
    __builtin_amdgcn_s_setprio(0);                                                 \
    __builtin_amdgcn_s_barrier();                                                  \
    /* P2 */                                                                       \
    _Pragma("unroll") for (int m = 0; m < 4; ++m)                                  \
      _Pragma("unroll") for (int kc = 0; kc < 2; ++kc)                             \
        afr[m][kc] = ORDA(D, 4 + m, kc);                                           \
    if (PRE) { OSTAGE_B(D, KTN); }                                                 \
    __builtin_amdgcn_s_barrier();                                                  \
    __builtin_amdgcn_s_setprio(1);                                                 \
    OMFMA8(4, 1)                                                                   \
    __builtin_amdgcn_s_setprio(0);                                                 \
    __builtin_amdgcn_s_barrier();                                                  \
    /* P3 */                                                                       \
    if (PRE) {                                                                     \
      OSTAGE_A(D, KTN);                                                            \
      asm volatile("s_waitcnt vmcnt(6)" ::: "memory");                             \
    } else {                                                                       \
      asm volatile("s_waitcnt vmcnt(0)" ::: "memory");                             \
    }                                                                              \
    __builtin_amdgcn_s_barrier();                                                  \
    __builtin_amdgcn_s_setprio(1);                                                 \
    OMFMA8(4, 0)                                                                   \
    __builtin_amdgcn_s_setprio(0);                                                 \
    __builtin_amdgcn_s_barrier();                                                  \
  } while (0)

__global__ __launch_bounds__(512, 1) void k_gemm_o(
    const u16* __restrict__ A, const u16* __restrict__ Bt,
    const float* __restrict__ bo, float* __restrict__ C) {
  __shared__ u16 S[OBUFB];                    // 96 KiB (2 buffers x 48 KB)
  const int t = threadIdx.x, l = t & 63, w = t >> 6;
  const int lr = l & 15, lk = l >> 4;
  const int wm = w >> 2, wn = w & 3;
  const int m0 = blockIdx.y * 256, n0b = blockIdx.x * 128;

  int stOffE[2];
#pragma unroll
  for (int i = 0; i < 2; ++i) {
    const int e = i * 512 + t;
    const int r = e >> 3;
    stOffE[i] = r * KD + ((e & 7) ^ (r & 7)) * 8;
  }
  const int qb = lr * 128 + (((lr >> 2) & 1) << 6) + ((lk ^ (lr & 3)) << 4);
  const int aQ = wm * 16384 + qb;
  const int bQ = 32768 + wn * 4096 + qb;

  f32x4 acc[8][2] = {};
  bf16x8 afr[4][2], bfr[2][2];

  OSTAGE_A(0, 0);  OSTAGE_B(0, 0);
  OSTAGE_A(1, 64); OSTAGE_B(1, 64);
  asm volatile("s_waitcnt vmcnt(6)" ::: "memory");
  __builtin_amdgcn_s_barrier();

  for (int j = 0; j < 30; j += 2) {
    ITERO(0, (j + 2) * 64, true);
    ITERO(1, (j + 3) * 64, true);
  }
  ITERO(0, 0, false);
  ITERO(1, 0, false);

  const int gmB = m0 + wm * 128, gnB = n0b + wn * 32;
#pragma unroll
  for (int m = 0; m < 8; ++m) {
    const int row0 = gmB + m * 16 + lk * 4;
#pragma unroll
    for (int nt = 0; nt < 2; ++nt) {
      const int col = gnB + nt * 16 + lr;
      const float bias = bo[col];
#pragma unroll
      for (int r = 0; r < 4; ++r)
        C[(size_t)(row0 + r) * HID + col] = acc[m][nt][r] + bias;
    }
  }
}

// ================= Flash attention (round-12 version: QBLK=128, KVBLK=32) ======
#define ATTN_ITER(KS, VS, KN, VN, TTV, PRE)                                        \
  do {                                                                             \
    if (PRE) {                                                                     \
      const int t0n = ((start + (TTV) + 1) & (NT - 1)) * 32;                       \
      const u16* kbT = kbase + (size_t)t0n * NQKV;                                 \
      const u16* vbT = vbase + t0n;                                                \
      _Pragma("unroll")                                                            \
      for (int i = 0; i < 2; ++i) {                                                \
        gl16(kbT + kOffE[i], (KN) + (i * 256 + t) * 8);                            \
        gl16(vbT + vOffE[i], (VN) + (i * 256 + t) * 8);                            \
      }                                                                            \
      asm volatile("s_waitcnt vmcnt(4)" ::: "memory");                             \
    } else {                                                                       \
      asm volatile("s_waitcnt vmcnt(0)" ::: "memory");                             \
    }                                                                              \
    __builtin_amdgcn_s_barrier();                                                  \
    f32x4 sc[2][2] = {};                                                           \
    __builtin_amdgcn_s_setprio(1);                                                 \
    _Pragma("unroll")                                                              \
    for (int kk = 0; kk < 4; ++kk) {                                               \
      bf16x8 kf[2];                                                                \
      _Pragma("unroll")                                                            \
      for (int mk = 0; mk < 2; ++mk) {                                             \
        const int LIT = (mk << 12) ^ ((kk >> 1) << 7) ^ ((kk & 1) << 6) ^ (mk << 5); \
        kf[mk] = *(const bf16x8*)((const char*)(KS) + (kQ0 ^ LIT));                \
      }                                                                            \
      _Pragma("unroll")                                                            \
      for (int nq = 0; nq < 2; ++nq)                                               \
        _Pragma("unroll")                                                          \
        for (int mk = 0; mk < 2; ++mk)                                             \
          sc[nq][mk] = __builtin_amdgcn_mfma_f32_16x16x32_bf16(kf[mk], qf[nq][kk], sc[nq][mk], 0, 0, 0); \
    }                                                                              \
    __builtin_amdgcn_s_setprio(0);                                                 \
    bf16x8 pa[2];                                                                  \
    _Pragma("unroll")                                                              \
    for (int nq = 0; nq < 2; ++nq) {                                               \
      u32 w0 = pk2(FEXP2(sc[nq][0][0]), FEXP2(sc[nq][0][1]));                      \
      u32 w1 = pk2(FEXP2(sc[nq][0][2]), FEXP2(sc[nq][0][3]));                      \
      u32 w2 = pk2(FEXP2(sc[nq][1][0]), FEXP2(sc[nq][1][1]));                      \
      u32 w3 = pk2(FEXP2(sc[nq][1][2]), FEXP2(sc[nq][1][3]));                      \
      asm("v_permlane32_swap_b32 %0, %1" : "+v"(w0), "+v"(w2));                    \
      asm("v_permlane32_swap_b32 %0, %1" : "+v"(w1), "+v"(w3));                    \
      asm("v_permlane16_swap_b32 %0, %1" : "+v"(w0), "+v"(w2));                    \
      asm("v_permlane16_swap_b32 %0, %1" : "+v"(w1), "+v"(w3));                    \
      u32x4 u = {w0, w1, w2, w3};                                                  \
      pa[nq] = __builtin_bit_cast(bf16x8, u);                                      \
    }                                                                              \
    __builtin_amdgcn_s_setprio(1);                                                 \
    _Pragma("unroll")                                                              \
    for (int nq = 0; nq < 2; ++nq)                                                 \
      acc_s[nq] = __builtin_amdgcn_mfma_f32_16x16x32_bf16(pa[nq], vones, acc_s[nq], 0, 0, 0); \
    _Pragma("unroll")                                                              \
    for (int nd = 0; nd < 8; ++nd) {                                               \
      const bf16x8 vf = *(const bf16x8*)((const char*)(VS) + vQ0 + nd * 1024);     \
      _Pragma("unroll")                                                            \
      for (int nq = 0; nq < 2; ++nq)                                               \
        acc_o[nq][nd] = __builtin_amdgcn_mfma_f32_16x16x32_bf16(pa[nq], vf, acc_o[nq][nd], 0, 0, 0); \
    }                                                                              \
    __builtin_amdgcn_s_setprio(0);                                                 \
    __builtin_amdgcn_s_barrier();                                                  \
  } while (0)

__global__ __launch_bounds__(256, 2) void k_attn(
    const u16* __restrict__ qkv, const u16* __restrict__ vT, u16* __restrict__ o_ws) {
  __shared__ u16 smem[16384];                 // 32 KiB
  u16* const kb0 = smem;
  u16* const kb1 = smem + 4096;
  u16* const vb0 = smem + 8192;
  u16* const vb1 = smem + 12288;

  const int t = threadIdx.x, l = t & 63, w = t >> 6;
  const int lr = l & 15, lk = l >> 4;
  const int f = blockIdx.x;
  const int bg = f & 7;                        // XCD-pinned (b,g)
  const int h = (f >> 3) & 3;
  const int qt = f >> 5;
  const int b = bg >> 2, g = bg & 3;
  const int q0 = qt * 128;
  const int qcol = (g * HPGQ + h) * DH;
  const u16* qbase = qkv + (size_t)(b * SEQ) * NQKV;
  const u16* kbase = qbase + HID + g * DH;
  const u16* vbase = vT + (size_t)(b * GQ + g) * DH * SEQ;

  const int NT = SEQ / 32;
  const int start = (qt * 5 + h * 9) & (NT - 1);

  const int kQ0 = lr * 256 + ((lk ^ (lr & 7) ^ (lr >> 3)) << 4);
  const int vQ0 = lr * 64 + ((lk ^ ((lr >> 1) & 3)) << 4);
  int kOffE[2], vOffE[2];
#pragma unroll
  for (int i = 0; i < 2; ++i) {
    const int e = i * 256 + t;
    const int r = e >> 4, c = e & 15;
    kOffE[i] = r * NQKV + swz(r, c) * 8;
    const int rv = e >> 2, cv = e & 3;
    vOffE[i] = rv * SEQ + ((cv ^ ((rv >> 1) & 3)) * 8);
  }

  bf16x8 qf[2][4];
#pragma unroll
  for (int nq = 0; nq < 2; ++nq)
#pragma unroll
    for (int kk = 0; kk < 4; ++kk)
      qf[nq][kk] = *(const bf16x8*)(qbase + (size_t)(q0 + w * 32 + nq * 16 + lr) * NQKV +
                                    qcol + kk * 32 + lk * 8);

  {
    const int t00 = start * 32;
    const u16* kbT = kbase + (size_t)t00 * NQKV;
    const u16* vbT = vbase + t00;
#pragma unroll
    for (int i = 0; i < 2; ++i) {
      gl16(kbT + kOffE[i], kb0 + (i * 256 + t) * 8);
      gl16(vbT + vOffE[i], vb0 + (i * 256 + t) * 8);
    }
  }

  f32x4 acc_o[2][8] = {};
  f32x4 acc_s[2] = {};

  bf16x8 vones;
#pragma unroll
  for (int j = 0; j < 8; ++j) vones[j] = (lr == 0) ? (__bf16)1.0f : (__bf16)0.0f;

  for (int tp = 0; tp < NT - 2; tp += 2) {
    ATTN_ITER(kb0, vb0, kb1, vb1, tp, true);
    ATTN_ITER(kb1, vb1, kb0, vb0, tp + 1, true);
  }
  ATTN_ITER(kb0, vb0, kb1, vb1, NT - 2, true);
  ATTN_ITER(kb1, vb1, kb0, vb0, NT - 1, false);

#pragma unroll
  for (int nq = 0; nq < 2; ++nq)
#pragma unroll
    for (int r = 0; r < 4; ++r) {
      const float s = __shfl(acc_s[nq][r], l & 48);
      const float inv = 1.0f / s;
      const int q = q0 + w * 32 + nq * 16 + lk * 4 + r;
#pragma unroll
      for (int nd = 0; nd < 8; ++nd) {
        const int d = nd * 16 + lr;
        o_ws[(size_t)(b * SEQ + q) * HID + qcol + d] = f2bf(acc_o[nq][nd][r] * inv);
      }
    }
}

extern "C" void kernel_launch(void* const* d_in, const int* in_sizes, int n_in,
                              void* d_out, int out_size, void* d_ws, size_t ws_size,
                              hipStream_t stream) {
  const float* x  = (const float*)d_in[0];
  const float* Wq = (const float*)d_in[1];
  const float* bq = (const float*)d_in[2];
  const float* Wk = (const float*)d_in[3];
  const float* bk = (const float*)d_in[4];
  const float* Wv = (const float*)d_in[5];
  const float* bv = (const float*)d_in[6];
  const float* Wo = (const float*)d_in[7];
  const float* bo = (const float*)d_in[8];
  float* out = (float*)d_out;

  char* ws = (char*)d_ws;
  u16* x_bf  = (u16*)ws;  ws += (size_t)NTOK * KD * 2;        // 16 MiB (reused as o_ws later)
  u16* qkvT  = (u16*)ws;  ws += (size_t)NQKV * KD * 2;        // 12 MiB
  u16* WoT   = (u16*)ws;  ws += (size_t)HID * KD * 2;         //  8 MiB
  u16* qkv   = (u16*)ws;  ws += (size_t)NTOK * NQKV * 2;      // 24 MiB
  u16* vTb   = (u16*)ws;  ws += (size_t)NBATCH * GQ * DH * SEQ * 2;  // 4 MiB
  u16* o_ws  = x_bf;  // x_bf dead after QKV GEMM; attention output reuses it

  k_cvt_bf16<<<(NTOK * KD / 4 + 255) / 256, 256, 0, stream>>>(x, x_bf, NTOK * KD / 4);
  k_trans_all<<<dim3(64, 64, 4), dim3(32, 8), 0, stream>>>(Wq, Wk, Wv, Wo, qkvT, WoT);

  k_gemm_qkv<<<dim3(NQKV / 192, NTOK / 256), 512, 0, stream>>>(x_bf, qkvT, qkv, vTb, bq, bk, bv);
  k_attn<<<SEQ / 128 * NBATCH * GQ * HPGQ, 256, 0, stream>>>(qkv, vTb, o_ws);
  k_gemm_o<<<dim3(HID / 128, NTOK / 256), 512, 0, stream>>>(o_ws, WoT, bo, out);
}

// Round 15
// 183.256 us; speedup vs baseline: 1.0289x; 1.0010x over previous
//
#include <hip/hip_runtime.h>

#define HID   2048
#define KD    2048
#define GQ    4
#define HPGQ  4
#define DH    128
#define SEQ   2048
#define NBATCH 2
#define NTOK  (NBATCH * SEQ)   // 4096
#define NQKV  3072

typedef unsigned short u16;
typedef unsigned int   u32;
using bf16x8 = __attribute__((ext_vector_type(8))) __bf16;
using bf16x2 = __attribute__((ext_vector_type(2))) __bf16;
using f32x4  = __attribute__((ext_vector_type(4))) float;
using u32x4  = __attribute__((ext_vector_type(4))) u32;

#if __has_builtin(__builtin_amdgcn_exp2f)
#define FEXP2(x) __builtin_amdgcn_exp2f(x)
#else
#define FEXP2(x) exp2f(x)
#endif

// 1/sqrt(128) * log2(e): folded into Q projection so scores are in log2 domain
#define QSCALE 0.12751744f

__device__ __forceinline__ u16 f2bf(float f) {
  union { float f; u32 u; } v; v.f = f;
  u32 u = v.u + 0x7fffu + ((v.u >> 16) & 1u);
  return (u16)(u >> 16);
}

__device__ __forceinline__ u32 pk2(float a, float b) {
  bf16x2 t;
  t[0] = (__bf16)a;
  t[1] = (__bf16)b;
  return __builtin_bit_cast(u32, t);
}

__device__ __forceinline__ void gl16(const void* g, void* l) {
  __builtin_amdgcn_global_load_lds((const __attribute__((address_space(1))) u32*)g,
                                   (__attribute__((address_space(3))) u32*)l, 16, 0, 0);
}

// staging-side swizzle (only used OUTSIDE hot loops, for lane-invariant offsets)
__device__ __forceinline__ int swz(int r, int c) {
  return (c & ~7) | ((c ^ r ^ (r >> 3)) & 7);
}

// ---------------- fp32 -> bf16 elementwise convert (x) ----------------
__global__ __launch_bounds__(256) void k_cvt_bf16(const float* __restrict__ in,
                                                  u16* __restrict__ out, int n4) {
  int i = blockIdx.x * 256 + threadIdx.x;
  if (i < n4) {
    const float4 v = ((const float4*)in)[i];
    ushort4 o;
    o.x = f2bf(v.x); o.y = f2bf(v.y); o.z = f2bf(v.z); o.w = f2bf(v.w);
    ((ushort4*)out)[i] = o;
  }
}

// ---------------- all weight transposes fused (blockIdx.z selects matrix) ---------
__global__ __launch_bounds__(256) void k_trans_all(
    const float* __restrict__ Wq, const float* __restrict__ Wk,
    const float* __restrict__ Wv, const float* __restrict__ Wo,
    u16* __restrict__ qkvT, u16* __restrict__ WoT) {
  __shared__ float tile[32][33];
  const int z = blockIdx.z;
  const float* W = (z == 0) ? Wq : (z == 1) ? Wk : (z == 2) ? Wv : Wo;
  u16* WT = (z == 3) ? WoT : qkvT;
  const int N = (z == 1 || z == 2) ? 512 : 2048;
  const int rowoff = (z == 1) ? 2048 : (z == 2) ? 2560 : 0;
  const int n0 = blockIdx.x * 32;
  if (n0 >= N) return;
  const int tx = threadIdx.x, ty = threadIdx.y;
  const int k0 = blockIdx.y * 32;
#pragma unroll
  for (int i = 0; i < 4; ++i)
    tile[ty + 8 * i][tx] = W[(size_t)(k0 + ty + 8 * i) * N + (n0 + tx)];
  __syncthreads();
#pragma unroll
  for (int i = 0; i < 4; ++i)
    WT[(size_t)(rowoff + n0 + ty + 8 * i) * KD + (k0 + tx)] = f2bf(tile[tx][ty + 8 * i]);
}

// ================= 256x192 8-wave pipelined GEMM (QKV) =================
// grid 16x16 = 256 blocks = 1/CU. BK=64, 512 threads = 8 waves (2M x 4N),
// per-wave output 128x48 (8m x 3nt). LDS: 2 x (A 32KB + B 24KB) = 112 KiB.
// NEW: 2 barriers per K-tile. Per tile: read mh0+B -> MFMA mh0 x all (compiler
// lgkmcnt-paces; mh1 reads overlap MFMA tail) -> read mh1 -> lgkmcnt(0) ->
// barrier (all waves fully read D) -> stage t+2 into D -> vmcnt(7) (= previous
// tile's 7 loads drain; buffer D^1 ready) -> barrier -> MFMA mh1 x all.

#define BUFB 57344

#define STG128(OP, ROWB, KTB, LBYTE)                                               \
  { _Pragma("unroll") for (int i = 0; i < 2; ++i)                                  \
      gl16((OP) + (size_t)(ROWB) * KD + (KTB) + stOffE[i],                         \
           (u16*)((char*)S + (LBYTE)) + (i * 512 + t) * 8); }
#define STG64(OP, ROWB, KTB, LBYTE)                                                \
  gl16((OP) + (size_t)(ROWB) * KD + (KTB) + stOffE[0],                             \
       (u16*)((char*)S + (LBYTE)) + t * 8);

#define STAGE_B(D, KTB)                                                            \
  STG128(Bt, n0b,       (KTB), (D) * BUFB + 32768);                                \
  STG64 (Bt, n0b + 128, (KTB), (D) * BUFB + 49152);
#define STAGE_A(D, KTB)                                                            \
  STG128(A,  m0,        (KTB), (D) * BUFB + 0);                                    \
  STG128(A,  m0 + 128,  (KTB), (D) * BUFB + 16384);

#define RDA(D, M, KC) (*(const bf16x8*)((const char*)S + (D) * BUFB + (M) * 2048 + (aQ ^ ((KC) << 6))))
#define RDB(D, NT, KC) (*(const bf16x8*)((const char*)S + (D) * BUFB + (NT) * 2048 + (bQ ^ ((KC) << 6))))

#define MFMA8(MB, NT)                                                              \
  _Pragma("unroll") for (int m = 0; m < 4; ++m)                                    \
    _Pragma("unroll") for (int kc = 0; kc < 2; ++kc)                               \
      acc[(MB) + m][NT] = __builtin_amdgcn_mfma_f32_16x16x32_bf16(                 \
          afr[m][kc], bfr[NT][kc], acc[(MB) + m][NT], 0, 0, 0);

#define ITERQ(D, KTN, PRE)                                                         \
  do {                                                                             \
    /* read mh0 + all B */                                                         \
    _Pragma("unroll") for (int m = 0; m < 4; ++m)                                  \
      _Pragma("unroll") for (int kc = 0; kc < 2; ++kc)                             \
        afr[m][kc] = RDA(D, m, kc);                                                \
    _Pragma("unroll") for (int nt = 0; nt < 3; ++nt)                               \
      _Pragma("unroll") for (int kc = 0; kc < 2; ++kc)                             \
        bfr[nt][kc] = RDB(D, nt, kc);                                              \
    __builtin_amdgcn_s_setprio(1);                                                 \
    MFMA8(0, 0) MFMA8(0, 1) MFMA8(0, 2)                                            \
    __builtin_amdgcn_s_setprio(0);                                                 \
    /* read mh1 (WAR on afr: issues after last mh0 MFMA, overlaps pipe drain) */   \
    _Pragma("unroll") for (int m = 0; m < 4; ++m)                                  \
      _Pragma("unroll") for (int kc = 0; kc < 2; ++kc)                             \
        afr[m][kc] = RDA(D, 4 + m, kc);                                            \
    asm volatile("s_waitcnt lgkmcnt(0)" ::: "memory");                             \
    __builtin_amdgcn_s_barrier();      /* all waves fully read buffer D */         \
    if (PRE) {                                                                     \
      STAGE_B(D, KTN);                                                             \
      STAGE_A(D, KTN);                                                             \
      asm volatile("s_waitcnt vmcnt(7)" ::: "memory");                             \
    } else {                                                                       \
      asm volatile("s_waitcnt vmcnt(0)" ::: "memory");                             \
    }                                                                              \
    __builtin_amdgcn_s_barrier();      /* buffer D^1 staged & ready */             \
    __builtin_amdgcn_s_setprio(1);                                                 \
    MFMA8(4, 0) MFMA8(4, 1) MFMA8(4, 2)                                            \
    __builtin_amdgcn_s_setprio(0);                                                 \
  } while (0)

__global__ __launch_bounds__(512, 1) void k_gemm_qkv(
    const u16* __restrict__ A, const u16* __restrict__ Bt,
    u16* __restrict__ qkv, u16* __restrict__ vT,
    const float* __restrict__ bq, const float* __restrict__ bk,
    const float* __restrict__ bv) {
  __shared__ u16 S[BUFB];                     // 112 KiB
  const int t = threadIdx.x, l = t & 63, w = t >> 6;
  const int lr = l & 15, lk = l >> 4;
  const int wm = w >> 2, wn = w & 3;
  const int m0 = blockIdx.y * 256, n0b = blockIdx.x * 192;

  int stOffE[2];
#pragma unroll
  for (int i = 0; i < 2; ++i) {
    const int e = i * 512 + t;
    const int r = e >> 3;
    stOffE[i] = r * KD + ((e & 7) ^ (r & 7)) * 8;
  }
  const int qb = lr * 128 + (((lr >> 2) & 1) << 6) + ((lk ^ (lr & 3)) << 4);
  const int aQ = wm * 16384 + qb;
  const int bQ = 32768 + wn * 6144 + qb;

  f32x4 acc[8][3] = {};
  bf16x8 afr[4][2], bfr[3][2];

  STAGE_A(0, 0);  STAGE_B(0, 0);
  STAGE_A(1, 64); STAGE_B(1, 64);
  asm volatile("s_waitcnt vmcnt(7)" ::: "memory");
  __builtin_amdgcn_s_barrier();

  for (int j = 0; j < 30; j += 2) {
    ITERQ(0, (j + 2) * 64, true);
    ITERQ(1, (j + 3) * 64, true);
  }
  ITERQ(0, 0, false);
  ITERQ(1, 0, false);

  const int gmB = m0 + wm * 128, gnB = n0b + wn * 48;
#pragma unroll
  for (int m = 0; m < 8; ++m) {
    const int row0 = gmB + m * 16 + lk * 4;
#pragma unroll
    for (int nt = 0; nt < 3; ++nt) {
      const int col = gnB + nt * 16 + lr;
      float bias, qs = 1.0f;
      if (col < HID) { bias = bq[col]; qs = QSCALE; }
      else if (col < HID + 512) bias = bk[col - HID];
      else bias = bv[col - HID - 512];
      if (col < HID + 512) {
#pragma unroll
        for (int r = 0; r < 4; ++r)
          qkv[(size_t)(row0 + r) * NQKV + col] = f2bf((acc[m][nt][r] + bias) * qs);
      } else {
        const int gg = (col - 2560) >> 7, d = (col - 2560) & 127;
        const int b = row0 >> 11, s0 = row0 & 2047;
        ushort4 pk;
        pk.x = f2bf(acc[m][nt][0] + bias);
        pk.y = f2bf(acc[m][nt][1] + bias);
        pk.z = f2bf(acc[m][nt][2] + bias);
        pk.w = f2bf(acc[m][nt][3] + bias);
        *(ushort4*)(vT + ((size_t)(b * GQ + gg) * DH + d) * SEQ + s0) = pk;
      }
    }
  }
}

// ================= 256x128 8-wave pipelined GEMM (O projection) =================
// Same 2-barrier-per-tile schedule; 6 loads/tile -> vmcnt(6).
#define OBUFB 49152

#define OSTAGE_B(D, KTB)                                                           \
  STG128(Bt, n0b, (KTB), (D) * OBUFB + 32768);
#define OSTAGE_A(D, KTB)                                                           \
  STG128(A,  m0,       (KTB), (D) * OBUFB + 0);                                    \
  STG128(A,  m0 + 128, (KTB), (D) * OBUFB + 16384);

#define ORDA(D, M, KC) (*(const bf16x8*)((const char*)S + (D) * OBUFB + (M) * 2048 + (aQ ^ ((KC) << 6))))
#define ORDB(D, NT, KC) (*(const bf16x8*)((const char*)S + (D) * OBUFB + (NT) * 2048 + (bQ ^ ((KC) << 6))))

#define OMFMA8(MB, NT)                                                             \
  _Pragma("unroll") for (int m = 0; m < 4; ++m)                                    \
    _Pragma("unroll") for (int kc = 0; kc < 2; ++kc)                               \
      acc[(MB) + m][NT] = __builtin_amdgcn_mfma_f32_16x16x32_bf16(                 \
          afr[m][kc], bfr[NT][kc], acc[(MB) + m][NT], 0, 0, 0);

#define ITERO(D, KTN, PRE)                                                         \
  do {                                                                             \
    _Pragma("unroll") for (int m = 0; m < 4; ++m)                                  \
      _Pragma("unroll") for (int kc = 0; kc < 2; ++kc)                             \
        afr[m][kc] = ORDA(D, m, kc);                                               \
    _Pragma("unroll") for (int nt = 0; nt < 2; ++nt)                               \
      _Pragma("unroll") for (int kc = 0; kc < 2; ++kc)                             \
        bfr[nt][kc] = ORDB(D, nt, kc);                                             \
    __builtin_amdgcn_s_setprio(1);                                                 \
    OMFMA8(0, 0) OMFMA8(0, 1)                                                      \
    __builtin_amdgcn_s_setprio(0);                                                 \
    _Pragma("unroll") for (int m = 0; m < 4; ++m)                                  \
      _Pragma("unroll") for (int kc = 0; kc < 2; ++kc)                             \
        afr[m][kc] = ORDA(D, 4 + m, kc);                                           \
    asm volatile("s_waitcnt lgkmcnt(0)" ::: "memory");                             \
    __builtin_amdgcn_s_barrier();                                                  \
    if (PRE) {                                                                     \
      OSTAGE_B(D, KTN);                                                            \
      OSTAGE_A(D, KTN);                                                            \
      asm volatile("s_waitcnt vmcnt(6)" ::: "memory");                             \
    } else {                                                                       \
      asm volatile("s_waitcnt vmcnt(0)" ::: "memory");                             \
    }                                                                              \
    __builtin_amdgcn_s_barrier();                                                  \
    __builtin_amdgcn_s_setprio(1);                                                 \
    OMFMA8(4, 0) OMFMA8(4, 1)                                                      \
    __builtin_amdgcn_s_setprio(0);                                                 \
  } while (0)

__global__ __launch_bounds__(512, 1) void k_gemm_o(
    const u16* __restrict__ A, const u16* __restrict__ Bt,
    const float* __restrict__ bo, float* __restrict__ C) {
  __shared__ u16 S[OBUFB];                    // 96 KiB
  const int t = threadIdx.x, l = t & 63, w = t >> 6;
  const int lr = l & 15, lk = l >> 4;
  const int wm = w >> 2, wn = w & 3;
  const int m0 = blockIdx.y * 256, n0b = blockIdx.x * 128;

  int stOffE[2];
#pragma unroll
  for (int i = 0; i < 2; ++i) {
    const int e = i * 512 + t;
    const int r = e >> 3;
    stOffE[i] = r * KD + ((e & 7) ^ (r & 7)) * 8;
  }
  const int qb = lr * 128 + (((lr >> 2) & 1) << 6) + ((lk ^ (lr & 3)) << 4);
  const int aQ = wm * 16384 + qb;
  const int bQ = 32768 + wn * 4096 + qb;

  f32x4 acc[8][2] = {};
  bf16x8 afr[4][2], bfr[2][2];

  OSTAGE_A(0, 0);  OSTAGE_B(0, 0);
  OSTAGE_A(1, 64); OSTAGE_B(1, 64);
  asm volatile("s_waitcnt vmcnt(6)" ::: "memory");
  __builtin_amdgcn_s_barrier();

  for (int j = 0; j < 30; j += 2) {
    ITERO(0, (j + 2) * 64, true);
    ITERO(1, (j + 3) * 64, true);
  }
  ITERO(0, 0, false);
  ITERO(1, 0, false);

  const int gmB = m0 + wm * 128, gnB = n0b + wn * 32;
#pragma unroll
  for (int m = 0; m < 8; ++m) {
    const int row0 = gmB + m * 16 + lk * 4;
#pragma unroll
    for (int nt = 0; nt < 2; ++nt) {
      const int col = gnB + nt * 16 + lr;
      const float bias = bo[col];
#pragma unroll
      for (int r = 0; r < 4; ++r)
        C[(size_t)(row0 + r) * HID + col] = acc[m][nt][r] + bias;
    }
  }
}

// ================= Flash attention (round-12 version: QBLK=128, KVBLK=32) ======
#define ATTN_ITER(KS, VS, KN, VN, TTV, PRE)                                        \
  do {                                                                             \
    if (PRE) {                                                                     \
      const int t0n = ((start + (TTV) + 1) & (NT - 1)) * 32;                       \
      const u16* kbT = kbase + (size_t)t0n * NQKV;                                 \
      const u16* vbT = vbase + t0n;                                                \
      _Pragma("unroll")                                                            \
      for (int i = 0; i < 2; ++i) {                                                \
        gl16(kbT + kOffE[i], (KN) + (i * 256 + t) * 8);                            \
        gl16(vbT + vOffE[i], (VN) + (i * 256 + t) * 8);                            \
      }                                                                            \
      asm volatile("s_waitcnt vmcnt(4)" ::: "memory");                             \
    } else {                                                                       \
      asm volatile("s_waitcnt vmcnt(0)" ::: "memory");                             \
    }                                                                              \
    __builtin_amdgcn_s_barrier();                                                  \
    f32x4 sc[2][2] = {};                                                           \
    __builtin_amdgcn_s_setprio(1);                                                 \
    _Pragma("unroll")                                                              \
    for (int kk = 0; kk < 4; ++kk) {                                               \
      bf16x8 kf[2];                                                                \
      _Pragma("unroll")                                                            \
      for (int mk = 0; mk < 2; ++mk) {                                             \
        const int LIT = (mk << 12) ^ ((kk >> 1) << 7) ^ ((kk & 1) << 6) ^ (mk << 5); \
        kf[mk] = *(const bf16x8*)((const char*)(KS) + (kQ0 ^ LIT));                \
      }                                                                            \
      _Pragma("unroll")                                                            \
      for (int nq = 0; nq < 2; ++nq)                                               \
        _Pragma("unroll")                                                          \
        for (int mk = 0; mk < 2; ++mk)                                             \
          sc[nq][mk] = __builtin_amdgcn_mfma_f32_16x16x32_bf16(kf[mk], qf[nq][kk], sc[nq][mk], 0, 0, 0); \
    }                                                                              \
    __builtin_amdgcn_s_setprio(0);                                                 \
    bf16x8 pa[2];                                                                  \
    _Pragma("unroll")                                                              \
    for (int nq = 0; nq < 2; ++nq) {                                               \
      u32 w0 = pk2(FEXP2(sc[nq][0][0]), FEXP2(sc[nq][0][1]));                      \
      u32 w1 = pk2(FEXP2(sc[nq][0][2]), FEXP2(sc[nq][0][3]));                      \
      u32 w2 = pk2(FEXP2(sc[nq][1][0]), FEXP2(sc[nq][1][1]));                      \
      u32 w3 = pk2(FEXP2(sc[nq][1][2]), FEXP2(sc[nq][1][3]));                      \
      asm("v_permlane32_swap_b32 %0, %1" : "+v"(w0), "+v"(w2));                    \
      asm("v_permlane32_swap_b32 %0, %1" : "+v"(w1), "+v"(w3));                    \
      asm("v_permlane16_swap_b32 %0, %1" : "+v"(w0), "+v"(w2));                    \
      asm("v_permlane16_swap_b32 %0, %1" : "+v"(w1), "+v"(w3));                    \
      u32x4 u = {w0, w1, w2, w3};                                                  \
      pa[nq] = __builtin_bit_cast(bf16x8, u);                                      \
    }                                                                              \
    __builtin_amdgcn_s_setprio(1);                                                 \
    _Pragma("unroll")                                                              \
    for (int nq = 0; nq < 2; ++nq)                                                 \
      acc_s[nq] = __builtin_amdgcn_mfma_f32_16x16x32_bf16(pa[nq], vones, acc_s[nq], 0, 0, 0); \
    _Pragma("unroll")                                                              \
    for (int nd = 0; nd < 8; ++nd) {                                               \
      const bf16x8 vf = *(const bf16x8*)((const char*)(VS) + vQ0 + nd * 1024);     \
      _Pragma("unroll")                                                            \
      for (int nq = 0; nq < 2; ++nq)                                               \
        acc_o[nq][nd] = __builtin_amdgcn_mfma_f32_16x16x32_bf16(pa[nq], vf, acc_o[nq][nd], 0, 0, 0); \
    }                                                                              \
    __builtin_amdgcn_s_setprio(0);                                                 \
    __builtin_amdgcn_s_barrier();                                                  \
  } while (0)

__global__ __launch_bounds__(256, 2) void k_attn(
    const u16* __restrict__ qkv, const u16* __restrict__ vT, u16* __restrict__ o_ws) {
  __shared__ u16 smem[16384];                 // 32 KiB
  u16* const kb0 = smem;
  u16* const kb1 = smem + 4096;
  u16* const vb0 = smem + 8192;
  u16* const vb1 = smem + 12288;

  const int t = threadIdx.x, l = t & 63, w = t >> 6;
  const int lr = l & 15, lk = l >> 4;
  const int f = blockIdx.x;
  const int bg = f & 7;                        // XCD-pinned (b,g)
  const int h = (f >> 3) & 3;
  const int qt = f >> 5;
  const int b = bg >> 2, g = bg & 3;
  const int q0 = qt * 128;
  const int qcol = (g * HPGQ + h) * DH;
  const u16* qbase = qkv + (size_t)(b * SEQ) * NQKV;
  const u16* kbase = qbase + HID + g * DH;
  const u16* vbase = vT + (size_t)(b * GQ + g) * DH * SEQ;

  const int NT = SEQ / 32;
  const int start = (qt * 5 + h * 9) & (NT - 1);

  const int kQ0 = lr * 256 + ((lk ^ (lr & 7) ^ (lr >> 3)) << 4);
  const int vQ0 = lr * 64 + ((lk ^ ((lr >> 1) & 3)) << 4);
  int kOffE[2], vOffE[2];
#pragma unroll
  for (int i = 0; i < 2; ++i) {
    const int e = i * 256 + t;
    const int r = e >> 4, c = e & 15;
    kOffE[i] = r * NQKV + swz(r, c) * 8;
    const int rv = e >> 2, cv = e & 3;
    vOffE[i] = rv * SEQ + ((cv ^ ((rv >> 1) & 3)) * 8);
  }

  bf16x8 qf[2][4];
#pragma unroll
  for (int nq = 0; nq < 2; ++nq)
#pragma unroll
    for (int kk = 0; kk < 4; ++kk)
      qf[nq][kk] = *(const bf16x8*)(qbase + (size_t)(q0 + w * 32 + nq * 16 + lr) * NQKV +
                                    qcol + kk * 32 + lk * 8);

  {
    const int t00 = start * 32;
    const u16* kbT = kbase + (size_t)t00 * NQKV;
    const u16* vbT = vbase + t00;
#pragma unroll
    for (int i = 0; i < 2; ++i) {
      gl16(kbT + kOffE[i], kb0 + (i * 256 + t) * 8);
      gl16(vbT + vOffE[i], vb0 + (i * 256 + t) * 8);
    }
  }

  f32x4 acc_o[2][8] = {};
  f32x4 acc_s[2] = {};

  bf16x8 vones;
#pragma unroll
  for (int j = 0; j < 8; ++j) vones[j] = (lr == 0) ? (__bf16)1.0f : (__bf16)0.0f;

  for (int tp = 0; tp < NT - 2; tp += 2) {
    ATTN_ITER(kb0, vb0, kb1, vb1, tp, true);
    ATTN_ITER(kb1, vb1, kb0, vb0, tp + 1, true);
  }
  ATTN_ITER(kb0, vb0, kb1, vb1, NT - 2, true);
  ATTN_ITER(kb1, vb1, kb0, vb0, NT - 1, false);

#pragma unroll
  for (int nq = 0; nq < 2; ++nq)
#pragma unroll
    for (int r = 0; r < 4; ++r) {
      const float s = __shfl(acc_s[nq][r], l & 48);
      const float inv = 1.0f / s;
      const int q = q0 + w * 32 + nq * 16 + lk * 4 + r;
#pragma unroll
      for (int nd = 0; nd < 8; ++nd) {
        const int d = nd * 16 + lr;
        o_ws[(size_t)(b * SEQ + q) * HID + qcol + d] = f2bf(acc_o[nq][nd][r] * inv);
      }
    }
}

extern "C" void kernel_launch(void* const* d_in, const int* in_sizes, int n_in,
                              void* d_out, int out_size, void* d_ws, size_t ws_size,
                              hipStream_t stream) {
  const float* x  = (const float*)d_in[0];
  const float* Wq = (const float*)d_in[1];
  const float* bq = (const float*)d_in[2];
  const float* Wk = (const float*)d_in[3];
  const float* bk = (const float*)d_in[4];
  const float* Wv = (const float*)d_in[5];
  const float* bv = (const float*)d_in[6];
  const float* Wo = (const float*)d_in[7];
  const float* bo = (const float*)d_in[8];
  float* out = (float*)d_out;

  char* ws = (char*)d_ws;
  u16* x_bf  = (u16*)ws;  ws += (size_t)NTOK * KD * 2;        // 16 MiB (reused as o_ws later)
  u16* qkvT  = (u16*)ws;  ws += (size_t)NQKV * KD * 2;        // 12 MiB
  u16* WoT   = (u16*)ws;  ws += (size_t)HID * KD * 2;         //  8 MiB
  u16* qkv   = (u16*)ws;  ws += (size_t)NTOK * NQKV * 2;      // 24 MiB
  u16* vTb   = (u16*)ws;  ws += (size_t)NBATCH * GQ * DH * SEQ * 2;  // 4 MiB
  u16* o_ws  = x_bf;  // x_bf dead after QKV GEMM; attention output reuses it

  k_cvt_bf16<<<(NTOK * KD / 4 + 255) / 256, 256, 0, stream>>>(x, x_bf, NTOK * KD / 4);
  k_trans_all<<<dim3(64, 64, 4), dim3(32, 8), 0, stream>>>(Wq, Wk, Wv, Wo, qkvT, WoT);

  k_gemm_qkv<<<dim3(NQKV / 192, NTOK / 256), 512, 0, stream>>>(x_bf, qkvT, qkv, vTb, bq, bk, bv);
  k_attn<<<SEQ / 128 * NBATCH * GQ * HPGQ, 256, 0, stream>>>(qkv, vTb, o_ws);
  k_gemm_o<<<dim3(HID / 128, NTOK / 256), 512, 0, stream>>>(o_ws, WoT, bo, out);
}

// Round 17
// 179.729 us; speedup vs baseline: 1.0491x; 1.0196x over previous
//
#include <hip/hip_runtime.h>

#define HID   2048
#define KD    2048
#define GQ    4
#define HPGQ  4
#define DH    128
#define SEQ   2048
#define NBATCH 2
#define NTOK  (NBATCH * SEQ)   // 4096
#define NQKV  3072

typedef unsigned short u16;
typedef unsigned int   u32;
using bf16x8 = __attribute__((ext_vector_type(8))) __bf16;
using bf16x2 = __attribute__((ext_vector_type(2))) __bf16;
using f32x4  = __attribute__((ext_vector_type(4))) float;
using u32x4  = __attribute__((ext_vector_type(4))) u32;

#if __has_builtin(__builtin_amdgcn_exp2f)
#define FEXP2(x) __builtin_amdgcn_exp2f(x)
#else
#define FEXP2(x) exp2f(x)
#endif

// 1/sqrt(128) * log2(e): folded into Q projection so scores are in log2 domain
#define QSCALE 0.12751744f

__device__ __forceinline__ u16 f2bf(float f) {
  union { float f; u32 u; } v; v.f = f;
  u32 u = v.u + 0x7fffu + ((v.u >> 16) & 1u);
  return (u16)(u >> 16);
}

__device__ __forceinline__ u32 pk2(float a, float b) {
  bf16x2 t;
  t[0] = (__bf16)a;
  t[1] = (__bf16)b;
  return __builtin_bit_cast(u32, t);
}

__device__ __forceinline__ void gl16(const void* g, void* l) {
  __builtin_amdgcn_global_load_lds((const __attribute__((address_space(1))) u32*)g,
                                   (__attribute__((address_space(3))) u32*)l, 16, 0, 0);
}

// staging-side swizzle (only used OUTSIDE hot loops, for lane-invariant offsets)
__device__ __forceinline__ int swz(int r, int c) {
  return (c & ~7) | ((c ^ r ^ (r >> 3)) & 7);
}

// ---------------- fused prep: fp32->bf16 convert of x + all weight transposes ----
// blocks [0, 8192): x convert (4096x2048 fp32, float4 per thread)
// blocks [8192, 18432): 32x32 transpose tiles for Wq | Wk | Wv | Wo
__global__ __launch_bounds__(256) void k_prep(
    const float* __restrict__ x, u16* __restrict__ x_bf,
    const float* __restrict__ Wq, const float* __restrict__ Wk,
    const float* __restrict__ Wv, const float* __restrict__ Wo,
    u16* __restrict__ qkvT, u16* __restrict__ WoT) {
  __shared__ float tile[32][33];
  const int bid = blockIdx.x;
  if (bid < 8192) {
    const int i = bid * 256 + threadIdx.x;
    const float4 v = ((const float4*)x)[i];
    ushort4 o;
    o.x = f2bf(v.x); o.y = f2bf(v.y); o.z = f2bf(v.z); o.w = f2bf(v.w);
    ((ushort4*)x_bf)[i] = o;
    return;
  }
  int idx = bid - 8192;
  const float* W; u16* WT; int N, rowoff, bx, by;
  if (idx < 4096)      {             W = Wq; WT = qkvT; N = 2048; rowoff = 0;    bx = idx & 63; by = idx >> 6; }
  else if (idx < 5120) { idx -= 4096; W = Wk; WT = qkvT; N = 512;  rowoff = 2048; bx = idx & 15; by = idx >> 4; }
  else if (idx < 6144) { idx -= 5120; W = Wv; WT = qkvT; N = 512;  rowoff = 2560; bx = idx & 15; by = idx >> 4; }
  else                 { idx -= 6144; W = Wo; WT = WoT;  N = 2048; rowoff = 0;    bx = idx & 63; by = idx >> 6; }
  const int tx = threadIdx.x & 31, ty = threadIdx.x >> 5;
  const int k0 = by * 32, n0 = bx * 32;
#pragma unroll
  for (int i = 0; i < 4; ++i)
    tile[ty + 8 * i][tx] = W[(size_t)(k0 + ty + 8 * i) * N + (n0 + tx)];
  __syncthreads();
#pragma unroll
  for (int i = 0; i < 4; ++i)
    WT[(size_t)(rowoff + n0 + ty + 8 * i) * KD + (k0 + tx)] = f2bf(tile[tx][ty + 8 * i]);
}

// ================= 256x192 8-wave pipelined GEMM (QKV) — round-15 version ========
#define BUFB 57344

#define STG128(OP, ROWB, KTB, LBYTE)                                               \
  { _Pragma("unroll") for (int i = 0; i < 2; ++i)                                  \
      gl16((OP) + (size_t)(ROWB) * KD + (KTB) + stOffE[i],                         \
           (u16*)((char*)S + (LBYTE)) + (i * 512 + t) * 8); }
#define STG64(OP, ROWB, KTB, LBYTE)                                                \
  gl16((OP) + (size_t)(ROWB) * KD + (KTB) + stOffE[0],                             \
       (u16*)((char*)S + (LBYTE)) + t * 8);

#define STAGE_B(D, KTB)                                                            \
  STG128(Bt, n0b,       (KTB), (D) * BUFB + 32768);                                \
  STG64 (Bt, n0b + 128, (KTB), (D) * BUFB + 49152);
#define STAGE_A(D, KTB)                                                            \
  STG128(A,  m0,        (KTB), (D) * BUFB + 0);                                    \
  STG128(A,  m0 + 128,  (KTB), (D) * BUFB + 16384);

#define RDA(D, M, KC) (*(const bf16x8*)((const char*)S + (D) * BUFB + (M) * 2048 + (aQ ^ ((KC) << 6))))
#define RDB(D, NT, KC) (*(const bf16x8*)((const char*)S + (D) * BUFB + (NT) * 2048 + (bQ ^ ((KC) << 6))))

#define MFMA8(MB, NT)                                                              \
  _Pragma("unroll") for (int m = 0; m < 4; ++m)                                    \
    _Pragma("unroll") for (int kc = 0; kc < 2; ++kc)                               \
      acc[(MB) + m][NT] = __builtin_amdgcn_mfma_f32_16x16x32_bf16(                 \
          afr[m][kc], bfr[NT][kc], acc[(MB) + m][NT], 0, 0, 0);

#define ITERQ(D, KTN, PRE)                                                         \
  do {                                                                             \
    _Pragma("unroll") for (int m = 0; m < 4; ++m)                                  \
      _Pragma("unroll") for (int kc = 0; kc < 2; ++kc)                             \
        afr[m][kc] = RDA(D, m, kc);                                                \
    _Pragma("unroll") for (int nt = 0; nt < 3; ++nt)                               \
      _Pragma("unroll") for (int kc = 0; kc < 2; ++kc)                             \
        bfr[nt][kc] = RDB(D, nt, kc);                                              \
    __builtin_amdgcn_s_setprio(1);                                                 \
    MFMA8(0, 0) MFMA8(0, 1) MFMA8(0, 2)                                            \
    __builtin_amdgcn_s_setprio(0);                                                 \
    _Pragma("unroll") for (int m = 0; m < 4; ++m)                                  \
      _Pragma("unroll") for (int kc = 0; kc < 2; ++kc)                             \
        afr[m][kc] = RDA(D, 4 + m, kc);                                            \
    asm volatile("s_waitcnt lgkmcnt(0)" ::: "memory");                             \
    __builtin_amdgcn_s_barrier();                                                  \
    if (PRE) {                                                                     \
      STAGE_B(D, KTN);                                                             \
      STAGE_A(D, KTN);                                                             \
      asm volatile("s_waitcnt vmcnt(7)" ::: "memory");                             \
    } else {                                                                       \
      asm volatile("s_waitcnt vmcnt(0)" ::: "memory");                             \
    }                                                                              \
    __builtin_amdgcn_s_barrier();                                                  \
    __builtin_amdgcn_s_setprio(1);                                                 \
    MFMA8(4, 0) MFMA8(4, 1) MFMA8(4, 2)                                            \
    __builtin_amdgcn_s_setprio(0);                                                 \
  } while (0)

__global__ __launch_bounds__(512, 1) void k_gemm_qkv(
    const u16* __restrict__ A, const u16* __restrict__ Bt,
    u16* __restrict__ qkv, u16* __restrict__ vT,
    const float* __restrict__ bq, const float* __restrict__ bk,
    const float* __restrict__ bv) {
  __shared__ u16 S[BUFB];                     // 112 KiB
  const int t = threadIdx.x, l = t & 63, w = t >> 6;
  const int lr = l & 15, lk = l >> 4;
  const int wm = w >> 2, wn = w & 3;
  const int m0 = blockIdx.y * 256, n0b = blockIdx.x * 192;

  int stOffE[2];
#pragma unroll
  for (int i = 0; i < 2; ++i) {
    const int e = i * 512 + t;
    const int r = e >> 3;
    stOffE[i] = r * KD + ((e & 7) ^ (r & 7)) * 8;
  }
  const int qb = lr * 128 + (((lr >> 2) & 1) << 6) + ((lk ^ (lr & 3)) << 4);
  const int aQ = wm * 16384 + qb;
  const int bQ = 32768 + wn * 6144 + qb;

  f32x4 acc[8][3] = {};
  bf16x8 afr[4][2], bfr[3][2];

  STAGE_A(0, 0);  STAGE_B(0, 0);
  STAGE_A(1, 64); STAGE_B(1, 64);
  asm volatile("s_waitcnt vmcnt(7)" ::: "memory");
  __builtin_amdgcn_s_barrier();

  for (int j = 0; j < 30; j += 2) {
    ITERQ(0, (j + 2) * 64, true);
    ITERQ(1, (j + 3) * 64, true);
  }
  ITERQ(0, 0, false);
  ITERQ(1, 0, false);

  const int gmB = m0 + wm * 128, gnB = n0b + wn * 48;
#pragma unroll
  for (int m = 0; m < 8; ++m) {
    const int row0 = gmB + m * 16 + lk * 4;
#pragma unroll
    for (int nt = 0; nt < 3; ++nt) {
      const int col = gnB + nt * 16 + lr;
      float bias, qs = 1.0f;
      if (col < HID) { bias = bq[col]; qs = QSCALE; }
      else if (col < HID + 512) bias = bk[col - HID];
      else bias = bv[col - HID - 512];
      if (col < HID + 512) {
#pragma unroll
        for (int r = 0; r < 4; ++r)
          qkv[(size_t)(row0 + r) * NQKV + col] = f2bf((acc[m][nt][r] + bias) * qs);
      } else {
        const int gg = (col - 2560) >> 7, d = (col - 2560) & 127;
        const int b = row0 >> 11, s0 = row0 & 2047;
        ushort4 pk;
        pk.x = f2bf(acc[m][nt][0] + bias);
        pk.y = f2bf(acc[m][nt][1] + bias);
        pk.z = f2bf(acc[m][nt][2] + bias);
        pk.w = f2bf(acc[m][nt][3] + bias);
        *(ushort4*)(vT + ((size_t)(b * GQ + gg) * DH + d) * SEQ + s0) = pk;
      }
    }
  }
}

// ================= 256x128 8-wave pipelined GEMM (O projection) — round-15 ======
#define OBUFB 49152

#define OSTAGE_B(D, KTB)                                                           \
  STG128(Bt, n0b, (KTB), (D) * OBUFB + 32768);
#define OSTAGE_A(D, KTB)                                                           \
  STG128(A,  m0,       (KTB), (D) * OBUFB + 0);                                    \
  STG128(A,  m0 + 128, (KTB), (D) * OBUFB + 16384);

#define ORDA(D, M, KC) (*(const bf16x8*)((const char*)S + (D) * OBUFB + (M) * 2048 + (aQ ^ ((KC) << 6))))
#define ORDB(D, NT, KC) (*(const bf16x8*)((const char*)S + (D) * OBUFB + (NT) * 2048 + (bQ ^ ((KC) << 6))))

#define OMFMA8(MB, NT)                                                             \
  _Pragma("unroll") for (int m = 0; m < 4; ++m)                                    \
    _Pragma("unroll") for (int kc = 0; kc < 2; ++kc)                               \
      acc[(MB) + m][NT] = __builtin_amdgcn_mfma_f32_16x16x32_bf16(                 \
          afr[m][kc], bfr[NT][kc], acc[(MB) + m][NT], 0, 0, 0);

#define ITERO(D, KTN, PRE)                                                         \
  do {                                                                             \
    _Pragma("unroll") for (int m = 0; m < 4; ++m)                                  \
      _Pragma("unroll") for (int kc = 0; kc < 2; ++kc)                             \
        afr[m][kc] = ORDA(D, m, kc);                                               \
    _Pragma("unroll") for (int nt = 0; nt < 2; ++nt)                               \
      _Pragma("unroll") for (int kc = 0; kc < 2; ++kc)                             \
        bfr[nt][kc] = ORDB(D, nt, kc);                                             \
    __builtin_amdgcn_s_setprio(1);                                                 \
    OMFMA8(0, 0) OMFMA8(0, 1)                                                      \
    __builtin_amdgcn_s_setprio(0);                                                 \
    _Pragma("unroll") for (int m = 0; m < 4; ++m)                                  \
      _Pragma("unroll") for (int kc = 0; kc < 2; ++kc)                             \
        afr[m][kc] = ORDA(D, 4 + m, kc);                                           \
    asm volatile("s_waitcnt lgkmcnt(0)" ::: "memory");                             \
    __builtin_amdgcn_s_barrier();                                                  \
    if (PRE) {                                                                     \
      OSTAGE_B(D, KTN);                                                            \
      OSTAGE_A(D, KTN);                                                            \
      asm volatile("s_waitcnt vmcnt(6)" ::: "memory");                             \
    } else {                                                                       \
      asm volatile("s_waitcnt vmcnt(0)" ::: "memory");                             \
    }                                                                              \
    __builtin_amdgcn_s_barrier();                                                  \
    __builtin_amdgcn_s_setprio(1);                                                 \
    OMFMA8(4, 0) OMFMA8(4, 1)                                                      \
    __builtin_amdgcn_s_setprio(0);                                                 \
  } while (0)

__global__ __launch_bounds__(512, 1) void k_gemm_o(
    const u16* __restrict__ A, const u16* __restrict__ Bt,
    const float* __restrict__ bo, float* __restrict__ C) {
  __shared__ u16 S[OBUFB];                    // 96 KiB
  const int t = threadIdx.x, l = t & 63, w = t >> 6;
  const int lr = l & 15, lk = l >> 4;
  const int wm = w >> 2, wn = w & 3;
  const int m0 = blockIdx.y * 256, n0b = blockIdx.x * 128;

  int stOffE[2];
#pragma unroll
  for (int i = 0; i < 2; ++i) {
    const int e = i * 512 + t;
    const int r = e >> 3;
    stOffE[i] = r * KD + ((e & 7) ^ (r & 7)) * 8;
  }
  const int qb = lr * 128 + (((lr >> 2) & 1) << 6) + ((lk ^ (lr & 3)) << 4);
  const int aQ = wm * 16384 + qb;
  const int bQ = 32768 + wn * 4096 + qb;

  f32x4 acc[8][2] = {};
  bf16x8 afr[4][2], bfr[2][2];

  OSTAGE_A(0, 0);  OSTAGE_B(0, 0);
  OSTAGE_A(1, 64); OSTAGE_B(1, 64);
  asm volatile("s_waitcnt vmcnt(6)" ::: "memory");
  __builtin_amdgcn_s_barrier();

  for (int j = 0; j < 30; j += 2) {
    ITERO(0, (j + 2) * 64, true);
    ITERO(1, (j + 3) * 64, true);
  }
  ITERO(0, 0, false);
  ITERO(1, 0, false);

  const int gmB = m0 + wm * 128, gnB = n0b + wn * 32;
#pragma unroll
  for (int m = 0; m < 8; ++m) {
    const int row0 = gmB + m * 16 + lk * 4;
#pragma unroll
    for (int nt = 0; nt < 2; ++nt) {
      const int col = gnB + nt * 16 + lr;
      const float bias = bo[col];
#pragma unroll
      for (int r = 0; r < 4; ++r)
        C[(size_t)(row0 + r) * HID + col] = acc[m][nt][r] + bias;
    }
  }
}

// ================= Flash attention (round-12 proven version: QBLK=128, KVBLK=32) ==
#define ATTN_ITER(KS, VS, KN, VN, TTV, PRE)                                        \
  do {                                                                             \
    if (PRE) {                                                                     \
      const int t0n = ((start + (TTV) + 1) & (NT - 1)) * 32;                       \
      const u16* kbT = kbase + (size_t)t0n * NQKV;                                 \
      const u16* vbT = vbase + t0n;                                                \
      _Pragma("unroll")                                                            \
      for (int i = 0; i < 2; ++i) {                                                \
        gl16(kbT + kOffE[i], (KN) + (i * 256 + t) * 8);                            \
        gl16(vbT + vOffE[i], (VN) + (i * 256 + t) * 8);                            \
      }                                                                            \
      asm volatile("s_waitcnt vmcnt(4)" ::: "memory");                             \
    } else {                                                                       \
      asm volatile("s_waitcnt vmcnt(0)" ::: "memory");                             \
    }                                                                              \
    __builtin_amdgcn_s_barrier();                                                  \
    f32x4 sc[2][2] = {};                                                           \
    __builtin_amdgcn_s_setprio(1);                                                 \
    _Pragma("unroll")                                                              \
    for (int kk = 0; kk < 4; ++kk) {                                               \
      bf16x8 kf[2];                                                                \
      _Pragma("unroll")                                                            \
      for (int mk = 0; mk < 2; ++mk) {                                             \
        const int LIT = (mk << 12) ^ ((kk >> 1) << 7) ^ ((kk & 1) << 6) ^ (mk << 5); \
        kf[mk] = *(const bf16x8*)((const char*)(KS) + (kQ0 ^ LIT));                \
      }                                                                            \
      _Pragma("unroll")                                                            \
      for (int nq = 0; nq < 2; ++nq)                                               \
        _Pragma("unroll")                                                          \
        for (int mk = 0; mk < 2; ++mk)                                             \
          sc[nq][mk] = __builtin_amdgcn_mfma_f32_16x16x32_bf16(kf[mk], qf[nq][kk], sc[nq][mk], 0, 0, 0); \
    }                                                                              \
    __builtin_amdgcn_s_setprio(0);                                                 \
    bf16x8 pa[2];                                                                  \
    _Pragma("unroll")                                                              \
    for (int nq = 0; nq < 2; ++nq) {                                               \
      u32 w0 = pk2(FEXP2(sc[nq][0][0]), FEXP2(sc[nq][0][1]));                      \
      u32 w1 = pk2(FEXP2(sc[nq][0][2]), FEXP2(sc[nq][0][3]));                      \
      u32 w2 = pk2(FEXP2(sc[nq][1][0]), FEXP2(sc[nq][1][1]));                      \
      u32 w3 = pk2(FEXP2(sc[nq][1][2]), FEXP2(sc[nq][1][3]));                      \
      asm("v_permlane32_swap_b32 %0, %1" : "+v"(w0), "+v"(w2));                    \
      asm("v_permlane32_swap_b32 %0, %1" : "+v"(w1), "+v"(w3));                    \
      asm("v_permlane16_swap_b32 %0, %1" : "+v"(w0), "+v"(w2));                    \
      asm("v_permlane16_swap_b32 %0, %1" : "+v"(w1), "+v"(w3));                    \
      u32x4 u = {w0, w1, w2, w3};                                                  \
      pa[nq] = __builtin_bit_cast(bf16x8, u);                                      \
    }                                                                              \
    __builtin_amdgcn_s_setprio(1);                                                 \
    _Pragma("unroll")                                                              \
    for (int nq = 0; nq < 2; ++nq)                                                 \
      acc_s[nq] = __builtin_amdgcn_mfma_f32_16x16x32_bf16(pa[nq], vones, acc_s[nq], 0, 0, 0); \
    _Pragma("unroll")                                                              \
    for (int nd = 0; nd < 8; ++nd) {                                               \
      const bf16x8 vf = *(const bf16x8*)((const char*)(VS) + vQ0 + nd * 1024);     \
      _Pragma("unroll")                                                            \
      for (int nq = 0; nq < 2; ++nq)                                               \
        acc_o[nq][nd] = __builtin_amdgcn_mfma_f32_16x16x32_bf16(pa[nq], vf, acc_o[nq][nd], 0, 0, 0); \
    }                                                                              \
    __builtin_amdgcn_s_setprio(0);                                                 \
    __builtin_amdgcn_s_barrier();                                                  \
  } while (0)

__global__ __launch_bounds__(256, 2) void k_attn(
    const u16* __restrict__ qkv, const u16* __restrict__ vT, u16* __restrict__ o_ws) {
  __shared__ u16 smem[16384];                 // 32 KiB
  u16* const kb0 = smem;
  u16* const kb1 = smem + 4096;
  u16* const vb0 = smem + 8192;
  u16* const vb1 = smem + 12288;

  const int t = threadIdx.x, l = t & 63, w = t >> 6;
  const int lr = l & 15, lk = l >> 4;
  const int f = blockIdx.x;
  const int bg = f & 7;                        // XCD-pinned (b,g)
  const int h = (f >> 3) & 3;
  const int qt = f >> 5;
  const int b = bg >> 2, g = bg & 3;
  const int q0 = qt * 128;
  const int qcol = (g * HPGQ + h) * DH;
  const u16* qbase = qkv + (size_t)(b * SEQ) * NQKV;
  const u16* kbase = qbase + HID + g * DH;
  const u16* vbase = vT + (size_t)(b * GQ + g) * DH * SEQ;

  const int NT = SEQ / 32;
  const int start = (qt * 5 + h * 9) & (NT - 1);

  const int kQ0 = lr * 256 + ((lk ^ (lr & 7) ^ (lr >> 3)) << 4);
  const int vQ0 = lr * 64 + ((lk ^ ((lr >> 1) & 3)) << 4);
  int kOffE[2], vOffE[2];
#pragma unroll
  for (int i = 0; i < 2; ++i) {
    const int e = i * 256 + t;
    const int r = e >> 4, c = e & 15;
    kOffE[i] = r * NQKV + swz(r, c) * 8;
    const int rv = e >> 2, cv = e & 3;
    vOffE[i] = rv * SEQ + ((cv ^ ((rv >> 1) & 3)) * 8);
  }

  bf16x8 qf[2][4];
#pragma unroll
  for (int nq = 0; nq < 2; ++nq)
#pragma unroll
    for (int kk = 0; kk < 4; ++kk)
      qf[nq][kk] = *(const bf16x8*)(qbase + (size_t)(q0 + w * 32 + nq * 16 + lr) * NQKV +
                                    qcol + kk * 32 + lk * 8);

  {
    const int t00 = start * 32;
    const u16* kbT = kbase + (size_t)t00 * NQKV;
    const u16* vbT = vbase + t00;
#pragma unroll
    for (int i = 0; i < 2; ++i) {
      gl16(kbT + kOffE[i], kb0 + (i * 256 + t) * 8);
      gl16(vbT + vOffE[i], vb0 + (i * 256 + t) * 8);
    }
  }

  f32x4 acc_o[2][8] = {};
  f32x4 acc_s[2] = {};

  bf16x8 vones;
#pragma unroll
  for (int j = 0; j < 8; ++j) vones[j] = (lr == 0) ? (__bf16)1.0f : (__bf16)0.0f;

  for (int tp = 0; tp < NT - 2; tp += 2) {
    ATTN_ITER(kb0, vb0, kb1, vb1, tp, true);
    ATTN_ITER(kb1, vb1, kb0, vb0, tp + 1, true);
  }
  ATTN_ITER(kb0, vb0, kb1, vb1, NT - 2, true);
  ATTN_ITER(kb1, vb1, kb0, vb0, NT - 1, false);

#pragma unroll
  for (int nq = 0; nq < 2; ++nq)
#pragma unroll
    for (int r = 0; r < 4; ++r) {
      const float s = __shfl(acc_s[nq][r], l & 48);
      const float inv = 1.0f / s;
      const int q = q0 + w * 32 + nq * 16 + lk * 4 + r;
#pragma unroll
      for (int nd = 0; nd < 8; ++nd) {
        const int d = nd * 16 + lr;
        o_ws[(size_t)(b * SEQ + q) * HID + qcol + d] = f2bf(acc_o[nq][nd][r] * inv);
      }
    }
}

extern "C" void kernel_launch(void* const* d_in, const int* in_sizes, int n_in,
                              void* d_out, int out_size, void* d_ws, size_t ws_size,
                              hipStream_t stream) {
  const float* x  = (const float*)d_in[0];
  const float* Wq = (const float*)d_in[1];
  const float* bq = (const float*)d_in[2];
  const float* Wk = (const float*)d_in[3];
  const float* bk = (const float*)d_in[4];
  const float* Wv = (const float*)d_in[5];
  const float* bv = (const float*)d_in[6];
  const float* Wo = (const float*)d_in[7];
  const float* bo = (const float*)d_in[8];
  float* out = (float*)d_out;

  char* ws = (char*)d_ws;
  u16* x_bf  = (u16*)ws;  ws += (size_t)NTOK * KD * 2;        // 16 MiB (reused as o_ws later)
  u16* qkvT  = (u16*)ws;  ws += (size_t)NQKV * KD * 2;        // 12 MiB
  u16* WoT   = (u16*)ws;  ws += (size_t)HID * KD * 2;         //  8 MiB
  u16* qkv   = (u16*)ws;  ws += (size_t)NTOK * NQKV * 2;      // 24 MiB
  u16* vTb   = (u16*)ws;  ws += (size_t)NBATCH * GQ * DH * SEQ * 2;  // 4 MiB
  u16* o_ws  = x_bf;  // x_bf dead after QKV GEMM; attention output reuses it

  k_prep<<<18432, 256, 0, stream>>>(x, x_bf, Wq, Wk, Wv, Wo, qkvT, WoT);

  k_gemm_qkv<<<dim3(NQKV / 192, NTOK / 256), 512, 0, stream>>>(x_bf, qkvT, qkv, vTb, bq, bk, bv);
  k_attn<<<SEQ / 128 * NBATCH * GQ * HPGQ, 256, 0, stream>>>(qkv, vTb, o_ws);
  k_gemm_o<<<dim3(HID / 128, NTOK / 256), 512, 0, stream>>>(o_ws, WoT, bo, out);
}